// Round 22
// baseline (567.253 us; speedup 1.0000x reference)
//
#include <hip/hip_runtime.h>
#include <hip/hip_bf16.h>
#include <stdint.h>

typedef __attribute__((ext_vector_type(8))) short short8;      // 8 bf16 (4 VGPRs) MFMA A/B frag
typedef __attribute__((ext_vector_type(8))) unsigned short ushort8;
typedef __attribute__((ext_vector_type(4))) unsigned short ushort4v;
typedef __attribute__((ext_vector_type(4))) float f32x4;       // MFMA C/D frag

#define DEV static __device__ __forceinline__

constexpr int Bc = 64, Sc = 512, Dc = 512, Hc = 8, DKc = 64, DFc = 2048;
constexpr int Mtot = Bc * Sc;   // 32768 rows total
constexpr int CB   = 16;        // batches per attention chunk (fallback path)
constexpr int RC   = CB * Sc;   // 8192 rows per chunk

// f32 -> bf16 round-to-nearest-even
DEV unsigned short f2b(float f) {
    union { float f; unsigned u; } x; x.f = f;
    unsigned r = x.u + 0x7fffu + ((x.u >> 16) & 1u);
    return (unsigned short)(r >> 16);
}
DEV float b2f(unsigned short u) {
    union { unsigned u; float f; } x; x.u = ((unsigned)u) << 16; return x.f;
}

// async global->LDS, 16B per lane; LDS dest is wave-uniform base (+lane*16 implicit)
DEV void gload16(const void* g, void* l) {
    __builtin_amdgcn_global_load_lds(
        (const __attribute__((address_space(1))) void*)g,
        (__attribute__((address_space(3))) void*)l, 16, 0, 0);
}

// ---------------- converts / copies ----------------
__global__ void k_cvt(const float* __restrict__ in, unsigned short* __restrict__ out, int n8) {
    int idx = blockIdx.x * 256 + threadIdx.x;
    if (idx >= n8) return;
    const float4* p = (const float4*)(in + (size_t)idx * 8);
    float4 a = p[0], b = p[1];
    ushort8 o;
    o[0] = f2b(a.x); o[1] = f2b(a.y); o[2] = f2b(a.z); o[3] = f2b(a.w);
    o[4] = f2b(b.x); o[5] = f2b(b.y); o[6] = f2b(b.z); o[7] = f2b(b.w);
    *(ushort8*)(out + (size_t)idx * 8) = o;
}

__global__ void k_copy8(const unsigned short* __restrict__ in, unsigned short* __restrict__ out, int n8) {
    int idx = blockIdx.x * 256 + threadIdx.x;
    if (idx >= n8) return;
    *(ushort8*)(out + (size_t)idx * 8) = *(const ushort8*)(in + (size_t)idx * 8);
}

// weight transpose group: COALESCED reads (consecutive lanes -> consecutive n), posted
// scattered 16B writes. li in [0, (K/8)*N): n = li % N, kc = li / N.
DEV void cvt_w_group(const float* __restrict__ in, unsigned short* __restrict__ out,
                     int K, int N, int li) {
    int n = li % N, kc = li / N;
    ushort8 o;
    #pragma unroll
    for (int j = 0; j < 8; ++j) o[j] = f2b(in[(size_t)(kc * 8 + j) * N + n]);
    *(ushort8*)(out + (size_t)n * K + kc * 8) = o;
}

// ALL weights -> bf16 transposed (chunked-path helper). Boundaries block-aligned.
__global__ void k_cvt_w_all(
    const float* __restrict__ Wq, const float* __restrict__ Wk, const float* __restrict__ Wv,
    const float* __restrict__ Wo, const float* __restrict__ W1, const float* __restrict__ W2,
    unsigned short* __restrict__ Wqt, unsigned short* __restrict__ Wkt,
    unsigned short* __restrict__ Wvt, unsigned short* __restrict__ Wot,
    unsigned short* __restrict__ W1t, unsigned short* __restrict__ W2t) {
    int idx = blockIdx.x * 256 + threadIdx.x;   // ushort8-group id, total 393216
    if (idx < 131072) {
        int w = idx >> 15, r = idx & 32767;
        const float* ins[4] = {Wq, Wk, Wv, Wo};
        unsigned short* outs[4] = {Wqt, Wkt, Wvt, Wot};
        cvt_w_group(ins[w], outs[w], 512, 512, r);
    } else if (idx < 262144) {
        cvt_w_group(W1, W1t, 512, 2048, idx - 131072);
    } else {
        cvt_w_group(W2, W2t, 2048, 512, idx - 262144);
    }
}

// BIG path: ALL weights (transposed) + ALL 3 activations (linear) in ONE dispatch.
// groups: [0,393216) weights | +2097152 query | +2097152 key | +2097152 vals. 26112 blocks.
__global__ void k_cvt_all(
    const float* __restrict__ Wq, const float* __restrict__ Wk, const float* __restrict__ Wv,
    const float* __restrict__ Wo, const float* __restrict__ W1, const float* __restrict__ W2,
    unsigned short* __restrict__ Wqt, unsigned short* __restrict__ Wkt,
    unsigned short* __restrict__ Wvt, unsigned short* __restrict__ Wot,
    unsigned short* __restrict__ W1t, unsigned short* __restrict__ W2t,
    const float* __restrict__ q_in, const float* __restrict__ k_in, const float* __restrict__ v_in,
    unsigned short* __restrict__ q_out, unsigned short* __restrict__ k_out,
    unsigned short* __restrict__ v_out) {
    int idx = blockIdx.x * 256 + threadIdx.x;
    if (idx >= 393216) {                          // activations: linear convert
        int a = idx - 393216;
        const float* in; unsigned short* out; int li;
        if (a < 2097152)       { in = q_in; out = q_out; li = a; }
        else if (a < 4194304)  { in = k_in; out = k_out; li = a - 2097152; }
        else                   { in = v_in; out = v_out; li = a - 4194304; }
        const float4* p = (const float4*)(in + (size_t)li * 8);
        float4 x = p[0], y = p[1];
        ushort8 o;
        o[0] = f2b(x.x); o[1] = f2b(x.y); o[2] = f2b(x.z); o[3] = f2b(x.w);
        o[4] = f2b(y.x); o[5] = f2b(y.y); o[6] = f2b(y.z); o[7] = f2b(y.w);
        *(ushort8*)(out + (size_t)li * 8) = o;
        return;
    }
    if (idx < 131072) {
        int w = idx >> 15, r = idx & 32767;
        const float* ins[4] = {Wq, Wk, Wv, Wo};
        unsigned short* outs[4] = {Wqt, Wkt, Wvt, Wot};
        cvt_w_group(ins[w], outs[w], 512, 512, r);
    } else if (idx < 262144) {
        cvt_w_group(W1, W1t, 512, 2048, idx - 131072);
    } else {
        cvt_w_group(W2, W2t, 2048, 512, idx - 262144);
    }
}

// ---------------- NT GEMM core: BK=64, 2-phase double-buffered (r12/r13/r18, verified) ----------------
template<int BM, int BN>
DEV void gemm_core(const unsigned short* __restrict__ A, int lda,
                   const unsigned short* __restrict__ Bt, int ldb, int K,
                   unsigned short* lA, unsigned short* lB,
                   f32x4 (&acc)[BM / 32][BN / 32]) {
    constexpr int MF = BM / 32, NF = BN / 32;
    const int tid = threadIdx.x, lane = tid & 63, wv = tid >> 6;
    const int wr = wv >> 1, wc = wv & 1;
    const int l15 = lane & 15, l4 = lane >> 4, l7 = l15 & 7;
    #pragma unroll
    for (int mf = 0; mf < MF; ++mf)
        #pragma unroll
        for (int nf = 0; nf < NF; ++nf)
            acc[mf][nf] = f32x4{0.f, 0.f, 0.f, 0.f};

    auto stage = [&](int buf, int kt0) {
        unsigned short* dA = lA + (size_t)buf * BM * 64;
        #pragma unroll
        for (int r = 0; r < BM / 32; ++r) {
            int c = r * 256 + tid, row = c >> 3, gs = c & 7;
            gload16(A + (size_t)row * lda + kt0 + ((gs ^ (row & 7)) * 8),
                    dA + (size_t)(r * 256 + wv * 64) * 8);
        }
        unsigned short* dB = lB + (size_t)buf * BN * 64;
        #pragma unroll
        for (int r = 0; r < BN / 32; ++r) {
            int c = r * 256 + tid, row = c >> 3, gs = c & 7;
            gload16(Bt + (size_t)row * ldb + kt0 + ((gs ^ (row & 7)) * 8),
                    dB + (size_t)(r * 256 + wv * 64) * 8);
        }
    };

    stage(0, 0);
    __syncthreads();                       // K-tile 0 landed
    const int nk = K / 64;
    for (int t = 0; t < nk; ++t) {
        const int buf = t & 1;
        if (t + 1 < nk) stage(buf ^ 1, (t + 1) * 64);   // prefetch next tile
        const unsigned short* cA = lA + (size_t)buf * BM * 64;
        const unsigned short* cB = lB + (size_t)buf * BN * 64;
        #pragma unroll
        for (int kt = 0; kt < 2; ++kt) {
            short8 af[MF], bfr[NF];
            #pragma unroll
            for (int mf = 0; mf < MF; ++mf)
                af[mf] = *(const short8*)&cA[(wr * (BM / 2) + mf * 16 + l15) * 64 +
                                             (((kt * 4 + l4) ^ l7) * 8)];
            #pragma unroll
            for (int nf = 0; nf < NF; ++nf)
                bfr[nf] = *(const short8*)&cB[(wc * (BN / 2) + nf * 16 + l15) * 64 +
                                              (((kt * 4 + l4) ^ l7) * 8)];
            #pragma unroll
            for (int mf = 0; mf < MF; ++mf)
                #pragma unroll
                for (int nf = 0; nf < NF; ++nf)
                    acc[mf][nf] = __builtin_amdgcn_mfma_f32_16x16x32_bf16(af[mf], bfr[nf], acc[mf][nf], 0, 0, 0);
        }
        __syncthreads();                   // drains prefetch (post-compute) + guards buf reuse
    }
}

// ---------------- QKV projection ----------------
// which: 0=Q (scale 1/8, [b,h,s,dk]), 1=K ([b,h,s,dk]), 2=V (transposed [b,h,dk,s])
__global__ __launch_bounds__(256) void k_gemm_qkv(
    const unsigned short* __restrict__ X, const unsigned short* __restrict__ Wt,
    const float* __restrict__ bias, unsigned short* __restrict__ out, int which) {
    __shared__ unsigned short lA[2 * 128 * 64], lB[2 * 128 * 64];
    int m0 = blockIdx.x * 128, n0 = blockIdx.y * 128;
    f32x4 acc[4][4];
    gemm_core<128, 128>(X + (size_t)m0 * Dc, Dc, Wt + (size_t)n0 * Dc, Dc, Dc, lA, lB, acc);
    const int lane = threadIdx.x & 63, wv = threadIdx.x >> 6;
    const int wr = wv >> 1, wc = wv & 1, l15 = lane & 15, l4 = lane >> 4;
    #pragma unroll
    for (int mf = 0; mf < 4; ++mf) {
        #pragma unroll
        for (int nf = 0; nf < 4; ++nf) {
            int n = n0 + wc * 64 + nf * 16 + l15;
            int h = n >> 6, dk = n & 63;
            float bv = bias[n];
            if (which == 2) {
                int mg = m0 + wr * 64 + mf * 16 + l4 * 4;  // 4 consecutive rows, same batch
                int b = mg >> 9, s = mg & 511;
                ushort4v o;
                #pragma unroll
                for (int r = 0; r < 4; ++r) o[r] = f2b(acc[mf][nf][r] + bv);
                *(ushort4v*)&out[((size_t)(b * Hc + h) * DKc + dk) * Sc + s] = o;
            } else {
                float scale = (which == 0) ? 0.125f : 1.0f;
                #pragma unroll
                for (int r = 0; r < 4; ++r) {
                    int mg = m0 + wr * 64 + mf * 16 + l4 * 4 + r;
                    int b = mg >> 9, s = mg & 511;
                    out[((size_t)(b * Hc + h) * Sc + s) * DKc + dk] = f2b((acc[mf][nf][r] + bv) * scale);
                }
            }
        }
    }
}

// ---------------- flash attention: QBLK=256, 8 waves, 2-phase KV-chunk pipeline (verified r21) ----------------
__global__ __launch_bounds__(512) void k_flash(
    const unsigned short* __restrict__ Qb, const unsigned short* __restrict__ Kb,
    const unsigned short* __restrict__ Vt, unsigned short* __restrict__ conc,
    const float* __restrict__ fr, const int* __restrict__ maskp, int b_base) {
    __shared__ unsigned short smem[32768];     // 64KB: lKb[2]@0/4096, lVb[2]@8192/12288, lP@16384
    const int head = blockIdx.y, bl = head >> 3, h = head & 7;
    const int bg = b_base + bl;                // global batch
    const int m0 = (Sc / 256 - 1 - blockIdx.x) * 256;   // LPT: longest blocks first
    const int mv = *maskp;
    const int tid = threadIdx.x, lane = tid & 63, w = tid >> 6;   // w in 0..7
    const int l15 = lane & 15, l4 = lane >> 4;
    const int l7 = l15 & 7;
    const int rw = w * 32;   // wave's q-row base within the 256-row tile
    unsigned short* lP = smem + 16384;         // [256][64]
    constexpr float LOG2E = 1.44269504088896340736f;

    // stage Q tile [256][64] across smem[0..16383] (lKb+lVb regions), source-swizzled
    unsigned short* lQ = smem;
    const unsigned short* Qg = Qb + ((size_t)head * Sc + m0) * DKc;
    #pragma unroll
    for (int r = 0; r < 4; ++r) {
        int c = r * 512 + tid, row = c >> 3, gs = c & 7;
        gload16(Qg + (size_t)row * DKc + ((gs ^ (row & 7)) * 8), lQ + (size_t)(r * 512 + w * 64) * 8);
    }
    __syncthreads();
    short8 qf[2][2];   // [kt][mf]
    #pragma unroll
    for (int kt = 0; kt < 2; ++kt)
        #pragma unroll
        for (int mf = 0; mf < 2; ++mf)
            qf[kt][mf] = *(const short8*)&lQ[(rw + mf * 16 + l15) * 64 + (((kt * 4 + l4) ^ l7) * 8)];
    float frr[8];      // forget_rate * log2e -> scores in log2 domain
    #pragma unroll
    for (int mf = 0; mf < 2; ++mf)
        #pragma unroll
        for (int r = 0; r < 4; ++r)
            frr[mf * 4 + r] = fr[(size_t)bg * Sc + m0 + rw + mf * 16 + l4 * 4 + r] * LOG2E;
    __syncthreads();   // all Q reads done before chunk staging overwrites the region

    f32x4 accO[2][4];  // [mf][dk-group of 16]
    #pragma unroll
    for (int mf = 0; mf < 2; ++mf)
        #pragma unroll
        for (int nf = 0; nf < 4; ++nf)
            accO[mf][nf] = f32x4{0.f, 0.f, 0.f, 0.f};
    float l_run[8];    // per-lane partial row sums (reduced once in epilogue)
    #pragma unroll
    for (int i = 0; i < 8; ++i) l_run[i] = 0.f;

    const unsigned short* Kg0 = Kb + (size_t)head * Sc * DKc;
    const unsigned short* Vg0 = Vt + (size_t)head * DKc * Sc;
    int nc = ((m0 + 254 + mv) >> 6) + 1;   // 64-col chunks needed (allowed: j < i + mv)
    if (nc > 8) nc = 8;
    if (nc < 1) nc = 1;

    // stage chunk 0 into buf 0 (64 rows x 64 cols K, 64 x 64 V^T; 1 gload16/thread each)
    {
        int row = tid >> 3, gs = tid & 7;
        gload16(Kg0 + (size_t)row * DKc + ((gs ^ (row & 7)) * 8), smem + (size_t)(w * 64) * 8);
        gload16(Vg0 + (size_t)row * Sc + ((gs ^ (row & 7)) * 8), smem + 8192 + (size_t)(w * 64) * 8);
    }
    __syncthreads();   // chunk 0 landed

    for (int ci = 0; ci < nc; ++ci) {
        const int buf = ci & 1;
        unsigned short* lK = smem + (size_t)buf * 4096;
        unsigned short* lV = smem + 8192 + (size_t)buf * 4096;
        // prefetch chunk ci+1 into buf^1 (drained by the barrier AFTER compute)
        if (ci + 1 < nc) {
            int n1 = (ci + 1) * 64;
            int row = tid >> 3, gs = tid & 7;
            gload16(Kg0 + (size_t)n1 * DKc + (size_t)row * DKc + ((gs ^ (row & 7)) * 8),
                    smem + (size_t)(buf ^ 1) * 4096 + (size_t)(w * 64) * 8);
            gload16(Vg0 + n1 + (size_t)row * Sc + ((gs ^ (row & 7)) * 8),
                    smem + 8192 + (size_t)(buf ^ 1) * 4096 + (size_t)(w * 64) * 8);
        }
        // ---- compute chunk ci from lK/lV ----
        const int n0c = ci * 64;
        short8 bk[4][2];   // 4 kv-groups x 2 k-halves
        #pragma unroll
        for (int j = 0; j < 4; ++j)
            #pragma unroll
            for (int kt = 0; kt < 2; ++kt)
                bk[j][kt] = *(const short8*)&lK[(j * 16 + l15) * 64 + (((kt * 4 + l4) ^ l7) * 8)];
        #pragma unroll
        for (int mf = 0; mf < 2; ++mf) {
            f32x4 sa[4];
            #pragma unroll
            for (int j = 0; j < 4; ++j) sa[j] = f32x4{0.f, 0.f, 0.f, 0.f};
            #pragma unroll
            for (int kt = 0; kt < 2; ++kt)
                #pragma unroll
                for (int j = 0; j < 4; ++j)
                    sa[j] = __builtin_amdgcn_mfma_f32_16x16x32_bf16(qf[kt][mf], bk[j][kt], sa[j], 0, 0, 0);
            // fixed-max softmax: p = exp2(s) raw, per-lane partial sums only
            #pragma unroll
            for (int r = 0; r < 4; ++r) {
                int rowl = rw + mf * 16 + l4 * 4 + r;
                int rowg = m0 + rowl;
                int prs = rowl & 7;
                float fres = frr[mf * 4 + r];
                float ps = 0.f;
                #pragma unroll
                for (int j = 0; j < 4; ++j) {
                    int colg = n0c + j * 16 + l15;
                    float p = (colg < rowg + mv) ? exp2f(sa[j][r] * fres) : 0.f;
                    ps += p;
                    int gw = j * 2 + (l15 >> 3);    // granule within chunk (0..7)
                    lP[rowl * 64 + ((gw ^ prs) * 8) + l7] = f2b(p);
                }
                l_run[mf * 4 + r] += ps;
            }
        }
        // O += P_chunk * V_chunk (2 k-slots of 32); wave-private lP stripe, in-order
        #pragma unroll
        for (int kl = 0; kl < 2; ++kl) {
            short8 pa[2];
            #pragma unroll
            for (int mf = 0; mf < 2; ++mf)
                pa[mf] = *(const short8*)&lP[(rw + mf * 16 + l15) * 64 + (((kl * 4 + l4) ^ l7) * 8)];
            #pragma unroll
            for (int nf = 0; nf < 4; ++nf) {
                short8 bv8 = *(const short8*)&lV[(nf * 16 + l15) * 64 + (((kl * 4 + l4) ^ l7) * 8)];
                #pragma unroll
                for (int mf = 0; mf < 2; ++mf)
                    accO[mf][nf] = __builtin_amdgcn_mfma_f32_16x16x32_bf16(pa[mf], bv8, accO[mf][nf], 0, 0, 0);
            }
        }
        __syncthreads();   // drains prefetch (post-compute) + guards buf reuse
    }
    // epilogue: reduce row sums across the 16-lane group, normalize; masked rows -> 0
    #pragma unroll
    for (int mf = 0; mf < 2; ++mf)
        #pragma unroll
        for (int r = 0; r < 4; ++r) {
            int rowg = m0 + rw + mf * 16 + l4 * 4 + r;
            float l = l_run[mf * 4 + r];
            #pragma unroll
            for (int o = 1; o < 16; o <<= 1) l += __shfl_xor(l, o);
            float inv = (rowg + mv > 0) ? 1.0f / l : 0.f;
            #pragma unroll
            for (int nf = 0; nf < 4; ++nf) {
                int dk = nf * 16 + l15;
                conc[((size_t)bg * Sc + rowg) * Dc + h * DKc + dk] = f2b(accO[mf][nf][r] * inv);
            }
        }
}

// ---------------- attn_out = concat * Wo + bo + query (residual), f32 out ----------------
__global__ __launch_bounds__(256) void k_wo(
    const unsigned short* __restrict__ Cc, const unsigned short* __restrict__ Wot,
    const float* __restrict__ bo, const float* __restrict__ query, float* __restrict__ y) {
    __shared__ unsigned short lA[2 * 128 * 64], lB[2 * 128 * 64];
    int m0 = blockIdx.x * 128, n0 = blockIdx.y * 128;
    f32x4 acc[4][4];
    gemm_core<128, 128>(Cc + (size_t)m0 * Dc, Dc, Wot + (size_t)n0 * Dc, Dc, Dc, lA, lB, acc);
    const int lane = threadIdx.x & 63, wv = threadIdx.x >> 6;
    const int wr = wv >> 1, wc = wv & 1, l15 = lane & 15, l4 = lane >> 4;
    #pragma unroll
    for (int mf = 0; mf < 4; ++mf)
        #pragma unroll
        for (int nf = 0; nf < 4; ++nf) {
            int n = n0 + wc * 64 + nf * 16 + l15;
            float bv = bo[n];
            #pragma unroll
            for (int r = 0; r < 4; ++r) {
                int m = m0 + wr * 64 + mf * 16 + l4 * 4 + r;
                y[(size_t)m * Dc + n] = acc[mf][nf][r] + bv + query[(size_t)m * Dc + n];
            }
        }
}

// ---------------- FF1: relu(x*W1 + b1) -> bf16 ----------------
__global__ __launch_bounds__(256) void k_ff1(
    const unsigned short* __restrict__ X, const unsigned short* __restrict__ W1t,
    const float* __restrict__ b1, unsigned short* __restrict__ hb) {
    __shared__ unsigned short lA[2 * 128 * 64], lB[2 * 128 * 64];
    int m0 = blockIdx.x * 128, n0 = blockIdx.y * 128;
    f32x4 acc[4][4];
    gemm_core<128, 128>(X + (size_t)m0 * Dc, Dc, W1t + (size_t)n0 * Dc, Dc, Dc, lA, lB, acc);
    const int lane = threadIdx.x & 63, wv = threadIdx.x >> 6;
    const int wr = wv >> 1, wc = wv & 1, l15 = lane & 15, l4 = lane >> 4;
    #pragma unroll
    for (int mf = 0; mf < 4; ++mf)
        #pragma unroll
        for (int nf = 0; nf < 4; ++nf) {
            int n = n0 + wc * 64 + nf * 16 + l15;
            float bv = b1[n];
            #pragma unroll
            for (int r = 0; r < 4; ++r) {
                int m = m0 + wr * 64 + mf * 16 + l4 * 4 + r;
                hb[(size_t)m * DFc + n] = f2b(fmaxf(acc[mf][nf][r] + bv, 0.f));
            }
        }
}

// ---------------- FF2: h*W2 + b2 + bf16 resid -> f32 out ----------------
__global__ __launch_bounds__(256) void k_ff2b(
    const unsigned short* __restrict__ Hb, const unsigned short* __restrict__ W2t,
    const float* __restrict__ b2, const unsigned short* __restrict__ residb,
    float* __restrict__ y) {
    __shared__ unsigned short lA[2 * 128 * 64], lB[2 * 128 * 64];
    int m0 = blockIdx.x * 128, n0 = blockIdx.y * 128;
    f32x4 acc[4][4];
    gemm_core<128, 128>(Hb + (size_t)m0 * DFc, DFc, W2t + (size_t)n0 * DFc, DFc, DFc, lA, lB, acc);
    const int lane = threadIdx.x & 63, wv = threadIdx.x >> 6;
    const int wr = wv >> 1, wc = wv & 1, l15 = lane & 15, l4 = lane >> 4;
    #pragma unroll
    for (int mf = 0; mf < 4; ++mf)
        #pragma unroll
        for (int nf = 0; nf < 4; ++nf) {
            int n = n0 + wc * 64 + nf * 16 + l15;
            float bv = b2[n];
            #pragma unroll
            for (int r = 0; r < 4; ++r) {
                int m = m0 + wr * 64 + mf * 16 + l4 * 4 + r;
                y[(size_t)m * Dc + n] = acc[mf][nf][r] + bv + b2f(residb[(size_t)m * Dc + n]);
            }
        }
}

// ---------------- LayerNorm (wave per row, D=512); in-place safe; outf/outb optional ----------------
__global__ __launch_bounds__(256) void k_ln(
    const float* __restrict__ in, const float* __restrict__ g, const float* __restrict__ be,
    float* __restrict__ outf, unsigned short* __restrict__ outb) {
    int rid = blockIdx.x * 4 + (threadIdx.x >> 6);
    int lane = threadIdx.x & 63;
    const float* row = in + (size_t)rid * Dc;
    float4 a = ((const float4*)row)[lane * 2];
    float4 b = ((const float4*)row)[lane * 2 + 1];
    float x[8] = {a.x, a.y, a.z, a.w, b.x, b.y, b.z, b.w};
    float s = 0.f, ss = 0.f;
    #pragma unroll
    for (int j = 0; j < 8; ++j) { s += x[j]; ss += x[j] * x[j]; }
    #pragma unroll
    for (int o = 1; o < 64; o <<= 1) { s += __shfl_xor(s, o); ss += __shfl_xor(ss, o); }
    float mu = s * (1.f / 512.f);
    float var = ss * (1.f / 512.f) - mu * mu;
    float rs = rsqrtf(var + 1e-5f);
    float4 g0 = ((const float4*)g)[lane * 2], g1v = ((const float4*)g)[lane * 2 + 1];
    float4 e0 = ((const float4*)be)[lane * 2], e1 = ((const float4*)be)[lane * 2 + 1];
    float gg[8] = {g0.x, g0.y, g0.z, g0.w, g1v.x, g1v.y, g1v.z, g1v.w};
    float ee[8] = {e0.x, e0.y, e0.z, e0.w, e1.x, e1.y, e1.z, e1.w};
    float o8[8];
    #pragma unroll
    for (int j = 0; j < 8; ++j) o8[j] = (x[j] - mu) * rs * gg[j] + ee[j];
    if (outf) {
        float4* po = (float4*)(outf + (size_t)rid * Dc);
        float4 w0 = {o8[0], o8[1], o8[2], o8[3]}, w1 = {o8[4], o8[5], o8[6], o8[7]};
        po[lane * 2] = w0; po[lane * 2 + 1] = w1;
    }
    if (outb) {
        ushort8 ob;
        #pragma unroll
        for (int j = 0; j < 8; ++j) ob[j] = f2b(o8[j]);
        *(ushort8*)(outb + (size_t)rid * Dc + lane * 8) = ob;
    }
}

// ---------------- host ----------------
// BIG path memory plan (ws >= 6MiB + 96MiB):
//   d_out: [0,32M) query-bf16 staging -> conc -> x1b -> final f32 out (descending FF)
//          [32,64M) key-bf16 staging (dead after K-GEMM)
//   ws:    [weights 6M][QbF 32M][KbF 32M][VtF 32M]
//   Region reuse timeline: cvt_all stages vals->KbF; V-GEMM KbF->VtF; K-GEMM d_out32->KbF;
//   Q-GEMM xb->QbF; flash QKV->conc; phase C xf(f32 64M) = KbF+VtF (dead); phase D
//   hb(64M)=QbF+KbF, resid0(16M)=VtF, Mc=16384.
//   Phase D proofs: chunk mb=16384 residual reads x1b bytes[16M,32M), out writes [32M,64M):
//   disjoint. mb=0 reads resid0 snapshot, writes [0,32M).
// Chunked fallback path = r15 (with QBLK=256 flash).
extern "C" void kernel_launch(void* const* d_in, const int* in_sizes, int n_in,
                              void* d_out, int out_size, void* d_ws, size_t ws_size,
                              hipStream_t stream) {
    const float* query = (const float*)d_in[0];
    const float* key_  = (const float*)d_in[1];
    const float* vals  = (const float*)d_in[2];
    const float* fr    = (const float*)d_in[3];
    const float* Wq = (const float*)d_in[4];  const float* bq = (const float*)d_in[5];
    const float* Wk = (const float*)d_in[6];  const float* bk = (const float*)d_in[7];
    const float* Wv = (const float*)d_in[8];  const float* bv = (const float*)d_in[9];
    const float* Wo = (const float*)d_in[10]; const float* bo = (const float*)d_in[11];
    const float* g1 = (const float*)d_in[12]; const float* be1 = (const float*)d_in[13];
    const float* W1 = (const float*)d_in[14]; const float* b1 = (const float*)d_in[15];
    const float* W2 = (const float*)d_in[16]; const float* b2 = (const float*)d_in[17];
    const float* g2 = (const float*)d_in[18]; const float* be2 = (const float*)d_in[19];
    const int* maskp = (const int*)d_in[20];
    float* out = (float*)d_out;

    // ---- d_out arena ----
    char* ab = (char*)d_out;
    unsigned short* xb    = (unsigned short*)ab;                   // 32 MiB
    unsigned short* conc  = (unsigned short*)ab;
    unsigned short* x1b   = conc;
    unsigned short* keyst = (unsigned short*)(ab + (size_t)32 * 1048576);  // big path
    // chunked-path per-chunk buffers (8 MiB each)
    unsigned short* Qc   = (unsigned short*)(ab + (size_t)32 * 1048576);
    unsigned short* Kc   = (unsigned short*)(ab + (size_t)40 * 1048576);
    unsigned short* Vc   = (unsigned short*)(ab + (size_t)48 * 1048576);
    unsigned short* xst  = (unsigned short*)(ab + (size_t)56 * 1048576);
    float*          xfc  = (float*)(ab + (size_t)32 * 1048576);    // chunked phase C (32M)

    // ---- ws layout ----
    char* ws = (char*)d_ws;
    unsigned short* Wqt = (unsigned short*)ws;
    unsigned short* Wkt = Wqt + 512 * 512;
    unsigned short* Wvt = Wkt + 512 * 512;
    unsigned short* Wot = Wvt + 512 * 512;
    unsigned short* W1t = Wot + 512 * 512;          // 2048x512
    unsigned short* W2t = W1t + 2048 * 512;         // 512x2048
    char* wend = (char*)(W2t + 512 * 2048);         // = ws + 6,291,456
    size_t wrem = (ws_size > (size_t)(wend - ws)) ? ws_size - (size_t)(wend - ws) : 0;
    const size_t qkvb = (size_t)Mtot * Dc * 2;      // 32 MiB

    const bool bigpath = (wrem >= 3 * qkvb);

    const float* acts[3] = {query, key_, vals};
    const unsigned short* wt3[3] = {Wqt, Wkt, Wvt};
    const float* bs3[3] = {bq, bk, bv};

    if (bigpath) {
        unsigned short* QbF = (unsigned short*)wend;
        unsigned short* KbF = QbF + qkvb / 2;
        unsigned short* VtF = KbF + qkvb / 2;
        unsigned short* hb     = QbF;           // 64 MiB (QbF+KbF), phase D only
        unsigned short* resid0 = VtF;           // 16 MiB (within VtF), phase D only
        float*          xf     = (float*)KbF;   // 64 MiB (KbF+VtF), phase C only
        const int Mc = 16384;

        // 1 dispatch: all weights + query->xb, key->keyst, vals->KbF(staging)
        k_cvt_all<<<dim3(26112), dim3(256), 0, stream>>>(
            Wq, Wk, Wv, Wo, W1, W2, Wqt, Wkt, Wvt, Wot, W1t, W2t,
            query, key_, vals, xb, keyst, KbF);

        // QKV GEMMs: V first (consumes KbF staging), then K (overwrites KbF), then Q
        k_gemm_qkv<<<dim3(Mtot / 128, 4), dim3(256), 0, stream>>>(KbF,   Wvt, bv, VtF, 2);
        k_gemm_qkv<<<dim3(Mtot / 128, 4), dim3(256), 0, stream>>>(keyst, Wkt, bk, KbF, 1);
        k_gemm_qkv<<<dim3(Mtot / 128, 4), dim3(256), 0, stream>>>(xb,    Wqt, bq, QbF, 0);

        k_flash<<<dim3(Sc / 256, Bc * Hc), dim3(512), 0, stream>>>(QbF, KbF, VtF, conc, fr, maskp, 0);

        // Phase C: single full pass (xf = 64 MiB in dead KbF+VtF)
        k_wo<<<dim3(Mtot / 128, 4), dim3(256), 0, stream>>>(conc, Wot, bo, query, xf);
        k_ln<<<dim3(Mtot / 4), dim3(256), 0, stream>>>(xf, g1, be1, (float*)nullptr, x1b);

        // snapshot x1b rows [0, Mc) -> resid0 (VtF; xf dead)
        k_copy8<<<dim3(Mc / 4), dim3(256), 0, stream>>>(x1b, resid0, Mc * Dc / 8);

        // Phase D: 2 chunks, descending
        for (int mb = Mtot - Mc; mb >= 0; mb -= Mc) {
            k_ff1<<<dim3(Mc / 128, 16), dim3(256), 0, stream>>>(x1b + (size_t)mb * Dc, W1t, b1, hb);
            k_ff2b<<<dim3(Mc / 128, 4), dim3(256), 0, stream>>>(hb, W2t, b2,
                                                                mb ? x1b + (size_t)mb * Dc : resid0,
                                                                out + (size_t)mb * Dc);
            k_ln<<<dim3(Mc / 4), dim3(256), 0, stream>>>(out + (size_t)mb * Dc, g2, be2,
                                                         out + (size_t)mb * Dc, (unsigned short*)nullptr);
        }
    } else {
        // ---- chunked fallback ----
        int Mc = 128;
        for (int c = 8192; c >= 128; c >>= 1)
            if ((size_t)c * 5120 <= wrem) { Mc = c; break; }
        unsigned short* hb     = (unsigned short*)wend;
        unsigned short* resid0 = (unsigned short*)(wend + (size_t)Mc * 4096);

        k_cvt_w_all<<<dim3(1536), dim3(256), 0, stream>>>(Wq, Wk, Wv, Wo, W1, W2,
                                                          Wqt, Wkt, Wvt, Wot, W1t, W2t);
        unsigned short* out3[3] = {Qc, Kc, Vc};
        for (int cb = 0; cb < Bc / CB; ++cb) {
            for (int p = 0; p < 3; ++p) {
                k_cvt<<<dim3(RC * Dc / 8 / 256), dim3(256), 0, stream>>>(
                    acts[p] + (size_t)cb * RC * Dc, xst, RC * Dc / 8);
                k_gemm_qkv<<<dim3(RC / 128, 4), dim3(256), 0, stream>>>(xst, wt3[p], bs3[p], out3[p], p);
            }
            k_flash<<<dim3(Sc / 256, CB * Hc), dim3(512), 0, stream>>>(Qc, Kc, Vc, conc, fr, maskp, cb * CB);
        }
        for (int hp = 0; hp < 2; ++hp) {
            int mb = hp * 16384;
            k_wo<<<dim3(16384 / 128, 4), dim3(256), 0, stream>>>(conc + (size_t)mb * Dc, Wot, bo,
                                                                 query + (size_t)mb * Dc, xfc);
            k_ln<<<dim3(16384 / 4), dim3(256), 0, stream>>>(xfc, g1, be1, (float*)nullptr,
                                                            x1b + (size_t)mb * Dc);
        }
        k_copy8<<<dim3(Mc / 4), dim3(256), 0, stream>>>(x1b, resid0, Mc * Dc / 8);
        for (int mb = Mtot - Mc; mb >= 0; mb -= Mc) {
            k_ff1<<<dim3(Mc / 128, 16), dim3(256), 0, stream>>>(x1b + (size_t)mb * Dc, W1t, b1, hb);
            k_ff2b<<<dim3(Mc / 128, 4), dim3(256), 0, stream>>>(hb, W2t, b2,
                                                                mb ? x1b + (size_t)mb * Dc : resid0,
                                                                out + (size_t)mb * Dc);
            k_ln<<<dim3(Mc / 4), dim3(256), 0, stream>>>(out + (size_t)mb * Dc, g2, be2,
                                                         out + (size_t)mb * Dc, (unsigned short*)nullptr);
        }
    }
}

// Round 23
// 558.780 us; speedup vs baseline: 1.0152x; 1.0152x over previous
//
#include <hip/hip_runtime.h>
#include <hip/hip_bf16.h>
#include <stdint.h>

typedef __attribute__((ext_vector_type(8))) short short8;      // 8 bf16 (4 VGPRs) MFMA A/B frag
typedef __attribute__((ext_vector_type(8))) unsigned short ushort8;
typedef __attribute__((ext_vector_type(4))) unsigned short ushort4v;
typedef __attribute__((ext_vector_type(4))) float f32x4;       // MFMA C/D frag

#define DEV static __device__ __forceinline__

constexpr int Bc = 64, Sc = 512, Dc = 512, Hc = 8, DKc = 64, DFc = 2048;
constexpr int Mtot = Bc * Sc;   // 32768 rows total
constexpr int CB   = 16;        // batches per attention chunk (fallback path)
constexpr int RC   = CB * Sc;   // 8192 rows per chunk

// f32 -> bf16 round-to-nearest-even
DEV unsigned short f2b(float f) {
    union { float f; unsigned u; } x; x.f = f;
    unsigned r = x.u + 0x7fffu + ((x.u >> 16) & 1u);
    return (unsigned short)(r >> 16);
}
DEV float b2f(unsigned short u) {
    union { unsigned u; float f; } x; x.u = ((unsigned)u) << 16; return x.f;
}

// async global->LDS, 16B per lane; LDS dest is wave-uniform base (+lane*16 implicit)
DEV void gload16(const void* g, void* l) {
    __builtin_amdgcn_global_load_lds(
        (const __attribute__((address_space(1))) void*)g,
        (__attribute__((address_space(3))) void*)l, 16, 0, 0);
}

// ---------------- converts / copies ----------------
__global__ void k_cvt(const float* __restrict__ in, unsigned short* __restrict__ out, int n8) {
    int idx = blockIdx.x * 256 + threadIdx.x;
    if (idx >= n8) return;
    const float4* p = (const float4*)(in + (size_t)idx * 8);
    float4 a = p[0], b = p[1];
    ushort8 o;
    o[0] = f2b(a.x); o[1] = f2b(a.y); o[2] = f2b(a.z); o[3] = f2b(a.w);
    o[4] = f2b(b.x); o[5] = f2b(b.y); o[6] = f2b(b.z); o[7] = f2b(b.w);
    *(ushort8*)(out + (size_t)idx * 8) = o;
}

__global__ void k_copy8(const unsigned short* __restrict__ in, unsigned short* __restrict__ out, int n8) {
    int idx = blockIdx.x * 256 + threadIdx.x;
    if (idx >= n8) return;
    *(ushort8*)(out + (size_t)idx * 8) = *(const ushort8*)(in + (size_t)idx * 8);
}

// weight transpose group: coalesced reads (consecutive lanes -> consecutive n)
DEV void cvt_w_group(const float* __restrict__ in, unsigned short* __restrict__ out,
                     int K, int N, int li) {
    int n = li % N, kc = li / N;
    ushort8 o;
    #pragma unroll
    for (int j = 0; j < 8; ++j) o[j] = f2b(in[(size_t)(kc * 8 + j) * N + n]);
    *(ushort8*)(out + (size_t)n * K + kc * 8) = o;
}

// ALL weights -> bf16 transposed (chunked-path helper). Boundaries block-aligned.
__global__ void k_cvt_w_all(
    const float* __restrict__ Wq, const float* __restrict__ Wk, const float* __restrict__ Wv,
    const float* __restrict__ Wo, const float* __restrict__ W1, const float* __restrict__ W2,
    unsigned short* __restrict__ Wqt, unsigned short* __restrict__ Wkt,
    unsigned short* __restrict__ Wvt, unsigned short* __restrict__ Wot,
    unsigned short* __restrict__ W1t, unsigned short* __restrict__ W2t) {
    int idx = blockIdx.x * 256 + threadIdx.x;   // ushort8-group id, total 393216
    if (idx < 131072) {
        int w = idx >> 15, r = idx & 32767;
        const float* ins[4] = {Wq, Wk, Wv, Wo};
        unsigned short* outs[4] = {Wqt, Wkt, Wvt, Wot};
        cvt_w_group(ins[w], outs[w], 512, 512, r);
    } else if (idx < 262144) {
        cvt_w_group(W1, W1t, 512, 2048, idx - 131072);
    } else {
        cvt_w_group(W2, W2t, 2048, 512, idx - 262144);
    }
}

// BIG path: ALL weights (transposed) + ALL 3 activations (linear) in ONE dispatch.
__global__ void k_cvt_all(
    const float* __restrict__ Wq, const float* __restrict__ Wk, const float* __restrict__ Wv,
    const float* __restrict__ Wo, const float* __restrict__ W1, const float* __restrict__ W2,
    unsigned short* __restrict__ Wqt, unsigned short* __restrict__ Wkt,
    unsigned short* __restrict__ Wvt, unsigned short* __restrict__ Wot,
    unsigned short* __restrict__ W1t, unsigned short* __restrict__ W2t,
    const float* __restrict__ q_in, const float* __restrict__ k_in, const float* __restrict__ v_in,
    unsigned short* __restrict__ q_out, unsigned short* __restrict__ k_out,
    unsigned short* __restrict__ v_out) {
    int idx = blockIdx.x * 256 + threadIdx.x;
    if (idx >= 393216) {                          // activations: linear convert
        int a = idx - 393216;
        const float* in; unsigned short* out; int li;
        if (a < 2097152)       { in = q_in; out = q_out; li = a; }
        else if (a < 4194304)  { in = k_in; out = k_out; li = a - 2097152; }
        else                   { in = v_in; out = v_out; li = a - 4194304; }
        const float4* p = (const float4*)(in + (size_t)li * 8);
        float4 x = p[0], y = p[1];
        ushort8 o;
        o[0] = f2b(x.x); o[1] = f2b(x.y); o[2] = f2b(x.z); o[3] = f2b(x.w);
        o[4] = f2b(y.x); o[5] = f2b(y.y); o[6] = f2b(y.z); o[7] = f2b(y.w);
        *(ushort8*)(out + (size_t)li * 8) = o;
        return;
    }
    if (idx < 131072) {
        int w = idx >> 15, r = idx & 32767;
        const float* ins[4] = {Wq, Wk, Wv, Wo};
        unsigned short* outs[4] = {Wqt, Wkt, Wvt, Wot};
        cvt_w_group(ins[w], outs[w], 512, 512, r);
    } else if (idx < 262144) {
        cvt_w_group(W1, W1t, 512, 2048, idx - 131072);
    } else {
        cvt_w_group(W2, W2t, 2048, 512, idx - 262144);
    }
}

// ---------------- NT GEMM core: BK=64, 2-phase double-buffered (verified r12/r18) ----------------
template<int BM, int BN>
DEV void gemm_core(const unsigned short* __restrict__ A, int lda,
                   const unsigned short* __restrict__ Bt, int ldb, int K,
                   unsigned short* lA, unsigned short* lB,
                   f32x4 (&acc)[BM / 32][BN / 32]) {
    constexpr int MF = BM / 32, NF = BN / 32;
    const int tid = threadIdx.x, lane = tid & 63, wv = tid >> 6;
    const int wr = wv >> 1, wc = wv & 1;
    const int l15 = lane & 15, l4 = lane >> 4, l7 = l15 & 7;
    #pragma unroll
    for (int mf = 0; mf < MF; ++mf)
        #pragma unroll
        for (int nf = 0; nf < NF; ++nf)
            acc[mf][nf] = f32x4{0.f, 0.f, 0.f, 0.f};

    auto stage = [&](int buf, int kt0) {
        unsigned short* dA = lA + (size_t)buf * BM * 64;
        #pragma unroll
        for (int r = 0; r < BM / 32; ++r) {
            int c = r * 256 + tid, row = c >> 3, gs = c & 7;
            gload16(A + (size_t)row * lda + kt0 + ((gs ^ (row & 7)) * 8),
                    dA + (size_t)(r * 256 + wv * 64) * 8);
        }
        unsigned short* dB = lB + (size_t)buf * BN * 64;
        #pragma unroll
        for (int r = 0; r < BN / 32; ++r) {
            int c = r * 256 + tid, row = c >> 3, gs = c & 7;
            gload16(Bt + (size_t)row * ldb + kt0 + ((gs ^ (row & 7)) * 8),
                    dB + (size_t)(r * 256 + wv * 64) * 8);
        }
    };

    stage(0, 0);
    __syncthreads();                       // K-tile 0 landed
    const int nk = K / 64;
    for (int t = 0; t < nk; ++t) {
        const int buf = t & 1;
        if (t + 1 < nk) stage(buf ^ 1, (t + 1) * 64);   // prefetch next tile
        const unsigned short* cA = lA + (size_t)buf * BM * 64;
        const unsigned short* cB = lB + (size_t)buf * BN * 64;
        #pragma unroll
        for (int kt = 0; kt < 2; ++kt) {
            short8 af[MF], bfr[NF];
            #pragma unroll
            for (int mf = 0; mf < MF; ++mf)
                af[mf] = *(const short8*)&cA[(wr * (BM / 2) + mf * 16 + l15) * 64 +
                                             (((kt * 4 + l4) ^ l7) * 8)];
            #pragma unroll
            for (int nf = 0; nf < NF; ++nf)
                bfr[nf] = *(const short8*)&cB[(wc * (BN / 2) + nf * 16 + l15) * 64 +
                                              (((kt * 4 + l4) ^ l7) * 8)];
            #pragma unroll
            for (int mf = 0; mf < MF; ++mf)
                #pragma unroll
                for (int nf = 0; nf < NF; ++nf)
                    acc[mf][nf] = __builtin_amdgcn_mfma_f32_16x16x32_bf16(af[mf], bfr[nf], acc[mf][nf], 0, 0, 0);
        }
        __syncthreads();                   // drains prefetch (post-compute) + guards buf reuse
    }
}

// ---------------- QKV epilogue (shared) ----------------
// which: 0=Q (scale 1/8, [b,h,s,dk]), 1=K ([b,h,s,dk]), 2=V (transposed [b,h,dk,s])
DEV void qkv_epilogue(f32x4 (&acc)[4][4], const float* __restrict__ bias,
                      unsigned short* __restrict__ out, int which, int m0, int n0) {
    const int lane = threadIdx.x & 63, wv = threadIdx.x >> 6;
    const int wr = wv >> 1, wc = wv & 1, l15 = lane & 15, l4 = lane >> 4;
    #pragma unroll
    for (int mf = 0; mf < 4; ++mf) {
        #pragma unroll
        for (int nf = 0; nf < 4; ++nf) {
            int n = n0 + wc * 64 + nf * 16 + l15;
            int h = n >> 6, dk = n & 63;
            float bv = bias[n];
            if (which == 2) {
                int mg = m0 + wr * 64 + mf * 16 + l4 * 4;  // 4 consecutive rows, same batch
                int b = mg >> 9, s = mg & 511;
                ushort4v o;
                #pragma unroll
                for (int r = 0; r < 4; ++r) o[r] = f2b(acc[mf][nf][r] + bv);
                *(ushort4v*)&out[((size_t)(b * Hc + h) * DKc + dk) * Sc + s] = o;
            } else {
                float scale = (which == 0) ? 0.125f : 1.0f;
                #pragma unroll
                for (int r = 0; r < 4; ++r) {
                    int mg = m0 + wr * 64 + mf * 16 + l4 * 4 + r;
                    int b = mg >> 9, s = mg & 511;
                    out[((size_t)(b * Hc + h) * Sc + s) * DKc + dk] = f2b((acc[mf][nf][r] + bv) * scale);
                }
            }
        }
    }
}

__global__ __launch_bounds__(256) void k_gemm_qkv(
    const unsigned short* __restrict__ X, const unsigned short* __restrict__ Wt,
    const float* __restrict__ bias, unsigned short* __restrict__ out, int which) {
    __shared__ unsigned short lA[2 * 128 * 64], lB[2 * 128 * 64];
    int m0 = blockIdx.x * 128, n0 = blockIdx.y * 128;
    f32x4 acc[4][4];
    gemm_core<128, 128>(X + (size_t)m0 * Dc, Dc, Wt + (size_t)n0 * Dc, Dc, Dc, lA, lB, acc);
    qkv_epilogue(acc, bias, out, which, m0, n0);
}

// merged QKV: grid.z selects {Q,K,V}; all inputs pre-staged in disjoint regions.
__global__ __launch_bounds__(256) void k_gemm_qkv3(
    const unsigned short* __restrict__ Aq, const unsigned short* __restrict__ Ak,
    const unsigned short* __restrict__ Av,
    const unsigned short* __restrict__ Wqt, const unsigned short* __restrict__ Wkt,
    const unsigned short* __restrict__ Wvt,
    const float* __restrict__ bq, const float* __restrict__ bk, const float* __restrict__ bv,
    unsigned short* __restrict__ oq, unsigned short* __restrict__ ok,
    unsigned short* __restrict__ ov) {
    __shared__ unsigned short lA[2 * 128 * 64], lB[2 * 128 * 64];
    const int which = blockIdx.z;
    const unsigned short* X  = which == 0 ? Aq  : (which == 1 ? Ak  : Av);
    const unsigned short* Wt = which == 0 ? Wqt : (which == 1 ? Wkt : Wvt);
    const float* bias        = which == 0 ? bq  : (which == 1 ? bk  : bv);
    unsigned short* out      = which == 0 ? oq  : (which == 1 ? ok  : ov);
    int m0 = blockIdx.x * 128, n0 = blockIdx.y * 128;
    f32x4 acc[4][4];
    gemm_core<128, 128>(X + (size_t)m0 * Dc, Dc, Wt + (size_t)n0 * Dc, Dc, Dc, lA, lB, acc);
    qkv_epilogue(acc, bias, out, which, m0, n0);
}

// ---------------- flash attention: QBLK=256, 8 waves, 2-phase KV-chunk pipeline (verified r21) ----------------
__global__ __launch_bounds__(512) void k_flash(
    const unsigned short* __restrict__ Qb, const unsigned short* __restrict__ Kb,
    const unsigned short* __restrict__ Vt, unsigned short* __restrict__ conc,
    const float* __restrict__ fr, const int* __restrict__ maskp, int b_base) {
    __shared__ unsigned short smem[32768];     // 64KB: lKb[2]@0/4096, lVb[2]@8192/12288, lP@16384
    const int head = blockIdx.y, bl = head >> 3, h = head & 7;
    const int bg = b_base + bl;                // global batch
    const int m0 = (Sc / 256 - 1 - blockIdx.x) * 256;   // LPT: longest blocks first
    const int mv = *maskp;
    const int tid = threadIdx.x, lane = tid & 63, w = tid >> 6;   // w in 0..7
    const int l15 = lane & 15, l4 = lane >> 4;
    const int l7 = l15 & 7;
    const int rw = w * 32;   // wave's q-row base within the 256-row tile
    unsigned short* lP = smem + 16384;         // [256][64]
    constexpr float LOG2E = 1.44269504088896340736f;

    // stage Q tile [256][64] across smem[0..16383] (lKb+lVb regions), source-swizzled
    unsigned short* lQ = smem;
    const unsigned short* Qg = Qb + ((size_t)head * Sc + m0) * DKc;
    #pragma unroll
    for (int r = 0; r < 4; ++r) {
        int c = r * 512 + tid, row = c >> 3, gs = c & 7;
        gload16(Qg + (size_t)row * DKc + ((gs ^ (row & 7)) * 8), lQ + (size_t)(r * 512 + w * 64) * 8);
    }
    __syncthreads();
    short8 qf[2][2];   // [kt][mf]
    #pragma unroll
    for (int kt = 0; kt < 2; ++kt)
        #pragma unroll
        for (int mf = 0; mf < 2; ++mf)
            qf[kt][mf] = *(const short8*)&lQ[(rw + mf * 16 + l15) * 64 + (((kt * 4 + l4) ^ l7) * 8)];
    float frr[8];      // forget_rate * log2e -> scores in log2 domain
    #pragma unroll
    for (int mf = 0; mf < 2; ++mf)
        #pragma unroll
        for (int r = 0; r < 4; ++r)
            frr[mf * 4 + r] = fr[(size_t)bg * Sc + m0 + rw + mf * 16 + l4 * 4 + r] * LOG2E;
    __syncthreads();   // all Q reads done before chunk staging overwrites the region

    f32x4 accO[2][4];  // [mf][dk-group of 16]
    #pragma unroll
    for (int mf = 0; mf < 2; ++mf)
        #pragma unroll
        for (int nf = 0; nf < 4; ++nf)
            accO[mf][nf] = f32x4{0.f, 0.f, 0.f, 0.f};
    float l_run[8];    // per-lane partial row sums (reduced once in epilogue)
    #pragma unroll
    for (int i = 0; i < 8; ++i) l_run[i] = 0.f;

    const unsigned short* Kg0 = Kb + (size_t)head * Sc * DKc;
    const unsigned short* Vg0 = Vt + (size_t)head * DKc * Sc;
    int nc = ((m0 + 254 + mv) >> 6) + 1;   // 64-col chunks needed (allowed: j < i + mv)
    if (nc > 8) nc = 8;
    if (nc < 1) nc = 1;

    // stage chunk 0 into buf 0 (64 rows x 64 cols K, 64 x 64 V^T; 1 gload16/thread each)
    {
        int row = tid >> 3, gs = tid & 7;
        gload16(Kg0 + (size_t)row * DKc + ((gs ^ (row & 7)) * 8), smem + (size_t)(w * 64) * 8);
        gload16(Vg0 + (size_t)row * Sc + ((gs ^ (row & 7)) * 8), smem + 8192 + (size_t)(w * 64) * 8);
    }
    __syncthreads();   // chunk 0 landed

    for (int ci = 0; ci < nc; ++ci) {
        const int buf = ci & 1;
        unsigned short* lK = smem + (size_t)buf * 4096;
        unsigned short* lV = smem + 8192 + (size_t)buf * 4096;
        // prefetch chunk ci+1 into buf^1 (drained by the barrier AFTER compute)
        if (ci + 1 < nc) {
            int n1 = (ci + 1) * 64;
            int row = tid >> 3, gs = tid & 7;
            gload16(Kg0 + (size_t)n1 * DKc + (size_t)row * DKc + ((gs ^ (row & 7)) * 8),
                    smem + (size_t)(buf ^ 1) * 4096 + (size_t)(w * 64) * 8);
            gload16(Vg0 + n1 + (size_t)row * Sc + ((gs ^ (row & 7)) * 8),
                    smem + 8192 + (size_t)(buf ^ 1) * 4096 + (size_t)(w * 64) * 8);
        }
        // ---- compute chunk ci from lK/lV ----
        const int n0c = ci * 64;
        short8 bk[4][2];   // 4 kv-groups x 2 k-halves
        #pragma unroll
        for (int j = 0; j < 4; ++j)
            #pragma unroll
            for (int kt = 0; kt < 2; ++kt)
                bk[j][kt] = *(const short8*)&lK[(j * 16 + l15) * 64 + (((kt * 4 + l4) ^ l7) * 8)];
        #pragma unroll
        for (int mf = 0; mf < 2; ++mf) {
            f32x4 sa[4];
            #pragma unroll
            for (int j = 0; j < 4; ++j) sa[j] = f32x4{0.f, 0.f, 0.f, 0.f};
            #pragma unroll
            for (int kt = 0; kt < 2; ++kt)
                #pragma unroll
                for (int j = 0; j < 4; ++j)
                    sa[j] = __builtin_amdgcn_mfma_f32_16x16x32_bf16(qf[kt][mf], bk[j][kt], sa[j], 0, 0, 0);
            // fixed-max softmax: p = exp2(s) raw, per-lane partial sums only
            #pragma unroll
            for (int r = 0; r < 4; ++r) {
                int rowl = rw + mf * 16 + l4 * 4 + r;
                int rowg = m0 + rowl;
                int prs = rowl & 7;
                float fres = frr[mf * 4 + r];
                float ps = 0.f;
                #pragma unroll
                for (int j = 0; j < 4; ++j) {
                    int colg = n0c + j * 16 + l15;
                    float p = (colg < rowg + mv) ? exp2f(sa[j][r] * fres) : 0.f;
                    ps += p;
                    int gw = j * 2 + (l15 >> 3);    // granule within chunk (0..7)
                    lP[rowl * 64 + ((gw ^ prs) * 8) + l7] = f2b(p);
                }
                l_run[mf * 4 + r] += ps;
            }
        }
        // O += P_chunk * V_chunk (2 k-slots of 32); wave-private lP stripe, in-order
        #pragma unroll
        for (int kl = 0; kl < 2; ++kl) {
            short8 pa[2];
            #pragma unroll
            for (int mf = 0; mf < 2; ++mf)
                pa[mf] = *(const short8*)&lP[(rw + mf * 16 + l15) * 64 + (((kl * 4 + l4) ^ l7) * 8)];
            #pragma unroll
            for (int nf = 0; nf < 4; ++nf) {
                short8 bv8 = *(const short8*)&lV[(nf * 16 + l15) * 64 + (((kl * 4 + l4) ^ l7) * 8)];
                #pragma unroll
                for (int mf = 0; mf < 2; ++mf)
                    accO[mf][nf] = __builtin_amdgcn_mfma_f32_16x16x32_bf16(pa[mf], bv8, accO[mf][nf], 0, 0, 0);
            }
        }
        __syncthreads();   // drains prefetch (post-compute) + guards buf reuse
    }
    // epilogue: reduce row sums across the 16-lane group, normalize; masked rows -> 0
    #pragma unroll
    for (int mf = 0; mf < 2; ++mf)
        #pragma unroll
        for (int r = 0; r < 4; ++r) {
            int rowg = m0 + rw + mf * 16 + l4 * 4 + r;
            float l = l_run[mf * 4 + r];
            #pragma unroll
            for (int o = 1; o < 16; o <<= 1) l += __shfl_xor(l, o);
            float inv = (rowg + mv > 0) ? 1.0f / l : 0.f;
            #pragma unroll
            for (int nf = 0; nf < 4; ++nf) {
                int dk = nf * 16 + l15;
                conc[((size_t)bg * Sc + rowg) * Dc + h * DKc + dk] = f2b(accO[mf][nf][r] * inv);
            }
        }
}

// ---------------- attn_out = concat * Wo + bo + query (residual) -> bf16 ----------------
__global__ __launch_bounds__(256) void k_wo(
    const unsigned short* __restrict__ Cc, const unsigned short* __restrict__ Wot,
    const float* __restrict__ bo, const float* __restrict__ query,
    unsigned short* __restrict__ y) {
    __shared__ unsigned short lA[2 * 128 * 64], lB[2 * 128 * 64];
    int m0 = blockIdx.x * 128, n0 = blockIdx.y * 128;
    f32x4 acc[4][4];
    gemm_core<128, 128>(Cc + (size_t)m0 * Dc, Dc, Wot + (size_t)n0 * Dc, Dc, Dc, lA, lB, acc);
    const int lane = threadIdx.x & 63, wv = threadIdx.x >> 6;
    const int wr = wv >> 1, wc = wv & 1, l15 = lane & 15, l4 = lane >> 4;
    #pragma unroll
    for (int mf = 0; mf < 4; ++mf)
        #pragma unroll
        for (int nf = 0; nf < 4; ++nf) {
            int n = n0 + wc * 64 + nf * 16 + l15;
            float bv = bo[n];
            #pragma unroll
            for (int r = 0; r < 4; ++r) {
                int m = m0 + wr * 64 + mf * 16 + l4 * 4 + r;
                y[(size_t)m * Dc + n] = f2b(acc[mf][nf][r] + bv + query[(size_t)m * Dc + n]);
            }
        }
}

// ---------------- FF1: relu(x*W1 + b1) -> bf16 ----------------
__global__ __launch_bounds__(256) void k_ff1(
    const unsigned short* __restrict__ X, const unsigned short* __restrict__ W1t,
    const float* __restrict__ b1, unsigned short* __restrict__ hb) {
    __shared__ unsigned short lA[2 * 128 * 64], lB[2 * 128 * 64];
    int m0 = blockIdx.x * 128, n0 = blockIdx.y * 128;
    f32x4 acc[4][4];
    gemm_core<128, 128>(X + (size_t)m0 * Dc, Dc, W1t + (size_t)n0 * Dc, Dc, Dc, lA, lB, acc);
    const int lane = threadIdx.x & 63, wv = threadIdx.x >> 6;
    const int wr = wv >> 1, wc = wv & 1, l15 = lane & 15, l4 = lane >> 4;
    #pragma unroll
    for (int mf = 0; mf < 4; ++mf)
        #pragma unroll
        for (int nf = 0; nf < 4; ++nf) {
            int n = n0 + wc * 64 + nf * 16 + l15;
            float bv = b1[n];
            #pragma unroll
            for (int r = 0; r < 4; ++r) {
                int m = m0 + wr * 64 + mf * 16 + l4 * 4 + r;
                hb[(size_t)m * DFc + n] = f2b(fmaxf(acc[mf][nf][r] + bv, 0.f));
            }
        }
}

// ---------------- FF2: h*W2 + b2 + bf16 resid -> bf16 out (DISJOINT buffers) ----------------
__global__ __launch_bounds__(256) void k_ff2bb(
    const unsigned short* __restrict__ Hb, const unsigned short* __restrict__ W2t,
    const float* __restrict__ b2, const unsigned short* __restrict__ residb,
    unsigned short* __restrict__ y) {
    __shared__ unsigned short lA[2 * 128 * 64], lB[2 * 128 * 64];
    int m0 = blockIdx.x * 128, n0 = blockIdx.y * 128;
    f32x4 acc[4][4];
    gemm_core<128, 128>(Hb + (size_t)m0 * DFc, DFc, W2t + (size_t)n0 * DFc, DFc, DFc, lA, lB, acc);
    const int lane = threadIdx.x & 63, wv = threadIdx.x >> 6;
    const int wr = wv >> 1, wc = wv & 1, l15 = lane & 15, l4 = lane >> 4;
    #pragma unroll
    for (int mf = 0; mf < 4; ++mf)
        #pragma unroll
        for (int nf = 0; nf < 4; ++nf) {
            int n = n0 + wc * 64 + nf * 16 + l15;
            float bv = b2[n];
            #pragma unroll
            for (int r = 0; r < 4; ++r) {
                int m = m0 + wr * 64 + mf * 16 + l4 * 4 + r;
                y[(size_t)m * Dc + n] = f2b(acc[mf][nf][r] + bv + b2f(residb[(size_t)m * Dc + n]));
            }
        }
}

// ---------------- LayerNorm, bf16 input (wave per row, D=512); outf/outb optional ----------------
__global__ __launch_bounds__(256) void k_lnb(
    const unsigned short* __restrict__ in, const float* __restrict__ g, const float* __restrict__ be,
    float* __restrict__ outf, unsigned short* __restrict__ outb) {
    int rid = blockIdx.x * 4 + (threadIdx.x >> 6);
    int lane = threadIdx.x & 63;
    ushort8 v = *(const ushort8*)(in + (size_t)rid * Dc + lane * 8);
    float x[8];
    #pragma unroll
    for (int j = 0; j < 8; ++j) x[j] = b2f(v[j]);
    float s = 0.f, ss = 0.f;
    #pragma unroll
    for (int j = 0; j < 8; ++j) { s += x[j]; ss += x[j] * x[j]; }
    #pragma unroll
    for (int o = 1; o < 64; o <<= 1) { s += __shfl_xor(s, o); ss += __shfl_xor(ss, o); }
    float mu = s * (1.f / 512.f);
    float var = ss * (1.f / 512.f) - mu * mu;
    float rs = rsqrtf(var + 1e-5f);
    float4 g0 = ((const float4*)g)[lane * 2], g1v = ((const float4*)g)[lane * 2 + 1];
    float4 e0 = ((const float4*)be)[lane * 2], e1 = ((const float4*)be)[lane * 2 + 1];
    float gg[8] = {g0.x, g0.y, g0.z, g0.w, g1v.x, g1v.y, g1v.z, g1v.w};
    float ee[8] = {e0.x, e0.y, e0.z, e0.w, e1.x, e1.y, e1.z, e1.w};
    float o8[8];
    #pragma unroll
    for (int j = 0; j < 8; ++j) o8[j] = (x[j] - mu) * rs * gg[j] + ee[j];
    if (outf) {
        float4* po = (float4*)(outf + (size_t)rid * Dc);
        float4 w0 = {o8[0], o8[1], o8[2], o8[3]}, w1 = {o8[4], o8[5], o8[6], o8[7]};
        po[lane * 2] = w0; po[lane * 2 + 1] = w1;
    }
    if (outb) {
        ushort8 ob;
        #pragma unroll
        for (int j = 0; j < 8; ++j) ob[j] = f2b(o8[j]);
        *(ushort8*)(outb + (size_t)rid * Dc + lane * 8) = ob;
    }
}

// ---------------- host ----------------
// BIG path (ws >= 6MiB + 96MiB; merged QKV additionally needs +32MiB for vals staging):
//   d_out: [0,32M) query-bf16 staging -> conc -> x1b -> final f32 out (descending FF)
//          [32,64M) key-bf16 staging (dead after K-GEMM)
//   ws:    [weights 6M][QbF 32M][KbF 32M][VtF 32M][valst 32M if merged]
//   Phase C: k_wo -> xfb (bf16, 16M in KbF, dead after flash); k_lnb -> x1b over conc.
//   Phase D: hb(64M)=QbF+KbF; resid0=VtF[0:16M); ybb=VtF[16M:32M); Mc=16384.
//     ff2bb: reads x1b rows + hb, writes ybb (disjoint). k_lnb: reads ybb, writes f32 out.
//     Clobber: chunk mb=16384 out bytes [32M,64M) vs x1b reads (rows<32768 -> bytes<32M) OK;
//     mb=0 reads resid0 snapshot.
extern "C" void kernel_launch(void* const* d_in, const int* in_sizes, int n_in,
                              void* d_out, int out_size, void* d_ws, size_t ws_size,
                              hipStream_t stream) {
    const float* query = (const float*)d_in[0];
    const float* key_  = (const float*)d_in[1];
    const float* vals  = (const float*)d_in[2];
    const float* fr    = (const float*)d_in[3];
    const float* Wq = (const float*)d_in[4];  const float* bq = (const float*)d_in[5];
    const float* Wk = (const float*)d_in[6];  const float* bk = (const float*)d_in[7];
    const float* Wv = (const float*)d_in[8];  const float* bv = (const float*)d_in[9];
    const float* Wo = (const float*)d_in[10]; const float* bo = (const float*)d_in[11];
    const float* g1 = (const float*)d_in[12]; const float* be1 = (const float*)d_in[13];
    const float* W1 = (const float*)d_in[14]; const float* b1 = (const float*)d_in[15];
    const float* W2 = (const float*)d_in[16]; const float* b2 = (const float*)d_in[17];
    const float* g2 = (const float*)d_in[18]; const float* be2 = (const float*)d_in[19];
    const int* maskp = (const int*)d_in[20];
    float* out = (float*)d_out;

    // ---- d_out arena ----
    char* ab = (char*)d_out;
    unsigned short* xb    = (unsigned short*)ab;                   // 32 MiB
    unsigned short* conc  = (unsigned short*)ab;
    unsigned short* x1b   = conc;
    unsigned short* keyst = (unsigned short*)(ab + (size_t)32 * 1048576);  // big path
    // chunked-path per-chunk buffers (8 MiB each)
    unsigned short* Qc   = (unsigned short*)(ab + (size_t)32 * 1048576);
    unsigned short* Kc   = (unsigned short*)(ab + (size_t)40 * 1048576);
    unsigned short* Vc   = (unsigned short*)(ab + (size_t)48 * 1048576);
    unsigned short* xst  = (unsigned short*)(ab + (size_t)56 * 1048576);
    unsigned short* xfbc = (unsigned short*)(ab + (size_t)32 * 1048576);   // chunked phase C (16M)

    // ---- ws layout ----
    char* ws = (char*)d_ws;
    unsigned short* Wqt = (unsigned short*)ws;
    unsigned short* Wkt = Wqt + 512 * 512;
    unsigned short* Wvt = Wkt + 512 * 512;
    unsigned short* Wot = Wvt + 512 * 512;
    unsigned short* W1t = Wot + 512 * 512;          // 2048x512
    unsigned short* W2t = W1t + 2048 * 512;         // 512x2048
    char* wend = (char*)(W2t + 512 * 2048);         // = ws + 6,291,456
    size_t wrem = (ws_size > (size_t)(wend - ws)) ? ws_size - (size_t)(wend - ws) : 0;
    const size_t qkvb = (size_t)Mtot * Dc * 2;      // 32 MiB

    const bool bigpath = (wrem >= 3 * qkvb);
    const bool merged  = (wrem >= 4 * qkvb);

    const float* acts[3] = {query, key_, vals};
    const unsigned short* wt3[3] = {Wqt, Wkt, Wvt};
    const float* bs3[3] = {bq, bk, bv};

    if (bigpath) {
        unsigned short* QbF   = (unsigned short*)wend;
        unsigned short* KbF   = QbF + qkvb / 2;
        unsigned short* VtF   = KbF + qkvb / 2;
        unsigned short* valst = VtF + qkvb / 2;     // merged path only (guarded)
        unsigned short* hb     = QbF;               // 64 MiB (QbF+KbF), phase D only
        unsigned short* resid0 = VtF;               // 16 MiB (VtF[0:16M)), phase D only
        unsigned short* ybb    = VtF + (size_t)8 * 1048576;  // 16 MiB (VtF[16M:32M))
        unsigned short* xfb    = KbF;               // 16 MiB used of KbF, phase C only
        const int Mc = 16384;

        if (merged) {
            // vals staged in 4th ws region -> all three GEMMs independent -> one dispatch
            k_cvt_all<<<dim3(26112), dim3(256), 0, stream>>>(
                Wq, Wk, Wv, Wo, W1, W2, Wqt, Wkt, Wvt, Wot, W1t, W2t,
                query, key_, vals, xb, keyst, valst);
            k_gemm_qkv3<<<dim3(Mtot / 128, 4, 3), dim3(256), 0, stream>>>(
                xb, keyst, valst, Wqt, Wkt, Wvt, bq, bk, bv, QbF, KbF, VtF);
        } else {
            // vals staged in KbF: V first (consumes it), then K (overwrites KbF), then Q
            k_cvt_all<<<dim3(26112), dim3(256), 0, stream>>>(
                Wq, Wk, Wv, Wo, W1, W2, Wqt, Wkt, Wvt, Wot, W1t, W2t,
                query, key_, vals, xb, keyst, KbF);
            k_gemm_qkv<<<dim3(Mtot / 128, 4), dim3(256), 0, stream>>>(KbF,   Wvt, bv, VtF, 2);
            k_gemm_qkv<<<dim3(Mtot / 128, 4), dim3(256), 0, stream>>>(keyst, Wkt, bk, KbF, 1);
            k_gemm_qkv<<<dim3(Mtot / 128, 4), dim3(256), 0, stream>>>(xb,    Wqt, bq, QbF, 0);
        }

        k_flash<<<dim3(Sc / 256, Bc * Hc), dim3(512), 0, stream>>>(QbF, KbF, VtF, conc, fr, maskp, 0);

        // Phase C: k_wo -> bf16 xfb (KbF, dead); k_lnb -> x1b (over conc)
        k_wo<<<dim3(Mtot / 128, 4), dim3(256), 0, stream>>>(conc, Wot, bo, query, xfb);
        k_lnb<<<dim3(Mtot / 4), dim3(256), 0, stream>>>(xfb, g1, be1, (float*)nullptr, x1b);

        // snapshot x1b rows [0, Mc) -> resid0 (VtF[0:16M); xfb/KbF now dead)
        k_copy8<<<dim3(Mc / 4), dim3(256), 0, stream>>>(x1b, resid0, Mc * Dc / 8);

        // Phase D: 2 chunks, descending; ff2 -> bf16 ybb (disjoint), LN2 bf16 -> f32 out
        for (int mb = Mtot - Mc; mb >= 0; mb -= Mc) {
            k_ff1<<<dim3(Mc / 128, 16), dim3(256), 0, stream>>>(x1b + (size_t)mb * Dc, W1t, b1, hb);
            k_ff2bb<<<dim3(Mc / 128, 4), dim3(256), 0, stream>>>(hb, W2t, b2,
                                                                 mb ? x1b + (size_t)mb * Dc : resid0,
                                                                 ybb);
            k_lnb<<<dim3(Mc / 4), dim3(256), 0, stream>>>(ybb, g2, be2,
                                                          out + (size_t)mb * Dc,
                                                          (unsigned short*)nullptr);
        }
    } else {
        // ---- chunked fallback ----
        int Mc = 128;
        for (int c = 8192; c >= 128; c >>= 1)
            if ((size_t)c * 6144 <= wrem) { Mc = c; break; }
        unsigned short* hb     = (unsigned short*)wend;                        // Mc*4096 B
        unsigned short* resid0 = (unsigned short*)(wend + (size_t)Mc * 4096);  // Mc*1024 B
        unsigned short* ybb    = (unsigned short*)(wend + (size_t)Mc * 5120);  // Mc*1024 B

        k_cvt_w_all<<<dim3(1536), dim3(256), 0, stream>>>(Wq, Wk, Wv, Wo, W1, W2,
                                                          Wqt, Wkt, Wvt, Wot, W1t, W2t);
        unsigned short* out3[3] = {Qc, Kc, Vc};
        for (int cb = 0; cb < Bc / CB; ++cb) {
            for (int p = 0; p < 3; ++p) {
                k_cvt<<<dim3(RC * Dc / 8 / 256), dim3(256), 0, stream>>>(
                    acts[p] + (size_t)cb * RC * Dc, xst, RC * Dc / 8);
                k_gemm_qkv<<<dim3(RC / 128, 4), dim3(256), 0, stream>>>(xst, wt3[p], bs3[p], out3[p], p);
            }
            k_flash<<<dim3(Sc / 256, CB * Hc), dim3(512), 0, stream>>>(Qc, Kc, Vc, conc, fr, maskp, cb * CB);
        }
        for (int hp = 0; hp < 2; ++hp) {
            int mb = hp * 16384;
            k_wo<<<dim3(16384 / 128, 4), dim3(256), 0, stream>>>(conc + (size_t)mb * Dc, Wot, bo,
                                                                 query + (size_t)mb * Dc, xfbc);
            k_lnb<<<dim3(16384 / 4), dim3(256), 0, stream>>>(xfbc, g1, be1, (float*)nullptr,
                                                             x1b + (size_t)mb * Dc);
        }
        k_copy8<<<dim3(Mc / 4), dim3(256), 0, stream>>>(x1b, resid0, Mc * Dc / 8);
        for (int mb = Mtot - Mc; mb >= 0; mb -= Mc) {
            k_ff1<<<dim3(Mc / 128, 16), dim3(256), 0, stream>>>(x1b + (size_t)mb * Dc, W1t, b1, hb);
            k_ff2bb<<<dim3(Mc / 128, 4), dim3(256), 0, stream>>>(hb, W2t, b2,
                                                                 mb ? x1b + (size_t)mb * Dc : resid0,
                                                                 ybb);
            k_lnb<<<dim3(Mc / 4), dim3(256), 0, stream>>>(ybb, g2, be2,
                                                          out + (size_t)mb * Dc,
                                                          (unsigned short*)nullptr);
        }
    }
}

// Round 24
// 556.939 us; speedup vs baseline: 1.0185x; 1.0033x over previous
//
#include <hip/hip_runtime.h>
#include <hip/hip_bf16.h>
#include <stdint.h>

typedef __attribute__((ext_vector_type(8))) short short8;      // 8 bf16 (4 VGPRs) MFMA A/B frag
typedef __attribute__((ext_vector_type(8))) unsigned short ushort8;
typedef __attribute__((ext_vector_type(4))) unsigned short ushort4v;
typedef __attribute__((ext_vector_type(4))) float f32x4;       // MFMA C/D frag

#define DEV static __device__ __forceinline__

constexpr int Bc = 64, Sc = 512, Dc = 512, Hc = 8, DKc = 64, DFc = 2048;
constexpr int Mtot = Bc * Sc;   // 32768 rows total
constexpr int CB   = 16;        // batches per attention chunk (fallback path)
constexpr int RC   = CB * Sc;   // 8192 rows per chunk

// f32 -> bf16 round-to-nearest-even
DEV unsigned short f2b(float f) {
    union { float f; unsigned u; } x; x.f = f;
    unsigned r = x.u + 0x7fffu + ((x.u >> 16) & 1u);
    return (unsigned short)(r >> 16);
}
DEV float b2f(unsigned short u) {
    union { unsigned u; float f; } x; x.u = ((unsigned)u) << 16; return x.f;
}

// async global->LDS, 16B per lane; LDS dest is wave-uniform base (+lane*16 implicit)
DEV void gload16(const void* g, void* l) {
    __builtin_amdgcn_global_load_lds(
        (const __attribute__((address_space(1))) void*)g,
        (__attribute__((address_space(3))) void*)l, 16, 0, 0);
}

// ---------------- converts / copies ----------------
__global__ void k_cvt(const float* __restrict__ in, unsigned short* __restrict__ out, int n8) {
    int idx = blockIdx.x * 256 + threadIdx.x;
    if (idx >= n8) return;
    const float4* p = (const float4*)(in + (size_t)idx * 8);
    float4 a = p[0], b = p[1];
    ushort8 o;
    o[0] = f2b(a.x); o[1] = f2b(a.y); o[2] = f2b(a.z); o[3] = f2b(a.w);
    o[4] = f2b(b.x); o[5] = f2b(b.y); o[6] = f2b(b.z); o[7] = f2b(b.w);
    *(ushort8*)(out + (size_t)idx * 8) = o;
}

__global__ void k_copy8(const unsigned short* __restrict__ in, unsigned short* __restrict__ out, int n8) {
    int idx = blockIdx.x * 256 + threadIdx.x;
    if (idx >= n8) return;
    *(ushort8*)(out + (size_t)idx * 8) = *(const ushort8*)(in + (size_t)idx * 8);
}

// weight transpose group: coalesced reads (consecutive lanes -> consecutive n)
DEV void cvt_w_group(const float* __restrict__ in, unsigned short* __restrict__ out,
                     int K, int N, int li) {
    int n = li % N, kc = li / N;
    ushort8 o;
    #pragma unroll
    for (int j = 0; j < 8; ++j) o[j] = f2b(in[(size_t)(kc * 8 + j) * N + n]);
    *(ushort8*)(out + (size_t)n * K + kc * 8) = o;
}

// ALL weights -> bf16 transposed (chunked-path helper). Boundaries block-aligned.
__global__ void k_cvt_w_all(
    const float* __restrict__ Wq, const float* __restrict__ Wk, const float* __restrict__ Wv,
    const float* __restrict__ Wo, const float* __restrict__ W1, const float* __restrict__ W2,
    unsigned short* __restrict__ Wqt, unsigned short* __restrict__ Wkt,
    unsigned short* __restrict__ Wvt, unsigned short* __restrict__ Wot,
    unsigned short* __restrict__ W1t, unsigned short* __restrict__ W2t) {
    int idx = blockIdx.x * 256 + threadIdx.x;   // ushort8-group id, total 393216
    if (idx < 131072) {
        int w = idx >> 15, r = idx & 32767;
        const float* ins[4] = {Wq, Wk, Wv, Wo};
        unsigned short* outs[4] = {Wqt, Wkt, Wvt, Wot};
        cvt_w_group(ins[w], outs[w], 512, 512, r);
    } else if (idx < 262144) {
        cvt_w_group(W1, W1t, 512, 2048, idx - 131072);
    } else {
        cvt_w_group(W2, W2t, 2048, 512, idx - 262144);
    }
}

// BIG path: ALL weights (transposed) + ALL 3 activations (linear) in ONE dispatch.
__global__ void k_cvt_all(
    const float* __restrict__ Wq, const float* __restrict__ Wk, const float* __restrict__ Wv,
    const float* __restrict__ Wo, const float* __restrict__ W1, const float* __restrict__ W2,
    unsigned short* __restrict__ Wqt, unsigned short* __restrict__ Wkt,
    unsigned short* __restrict__ Wvt, unsigned short* __restrict__ Wot,
    unsigned short* __restrict__ W1t, unsigned short* __restrict__ W2t,
    const float* __restrict__ q_in, const float* __restrict__ k_in, const float* __restrict__ v_in,
    unsigned short* __restrict__ q_out, unsigned short* __restrict__ k_out,
    unsigned short* __restrict__ v_out) {
    int idx = blockIdx.x * 256 + threadIdx.x;
    if (idx >= 393216) {                          // activations: linear convert
        int a = idx - 393216;
        const float* in; unsigned short* out; int li;
        if (a < 2097152)       { in = q_in; out = q_out; li = a; }
        else if (a < 4194304)  { in = k_in; out = k_out; li = a - 2097152; }
        else                   { in = v_in; out = v_out; li = a - 4194304; }
        const float4* p = (const float4*)(in + (size_t)li * 8);
        float4 x = p[0], y = p[1];
        ushort8 o;
        o[0] = f2b(x.x); o[1] = f2b(x.y); o[2] = f2b(x.z); o[3] = f2b(x.w);
        o[4] = f2b(y.x); o[5] = f2b(y.y); o[6] = f2b(y.z); o[7] = f2b(y.w);
        *(ushort8*)(out + (size_t)li * 8) = o;
        return;
    }
    if (idx < 131072) {
        int w = idx >> 15, r = idx & 32767;
        const float* ins[4] = {Wq, Wk, Wv, Wo};
        unsigned short* outs[4] = {Wqt, Wkt, Wvt, Wot};
        cvt_w_group(ins[w], outs[w], 512, 512, r);
    } else if (idx < 262144) {
        cvt_w_group(W1, W1t, 512, 2048, idx - 131072);
    } else {
        cvt_w_group(W2, W2t, 2048, 512, idx - 262144);
    }
}

// ---------------- NT GEMM core: BK=64, 2-phase double-buffered (verified r12/r18) ----------------
template<int BM, int BN>
DEV void gemm_core(const unsigned short* __restrict__ A, int lda,
                   const unsigned short* __restrict__ Bt, int ldb, int K,
                   unsigned short* lA, unsigned short* lB,
                   f32x4 (&acc)[BM / 32][BN / 32]) {
    constexpr int MF = BM / 32, NF = BN / 32;
    const int tid = threadIdx.x, lane = tid & 63, wv = tid >> 6;
    const int wr = wv >> 1, wc = wv & 1;
    const int l15 = lane & 15, l4 = lane >> 4, l7 = l15 & 7;
    #pragma unroll
    for (int mf = 0; mf < MF; ++mf)
        #pragma unroll
        for (int nf = 0; nf < NF; ++nf)
            acc[mf][nf] = f32x4{0.f, 0.f, 0.f, 0.f};

    auto stage = [&](int buf, int kt0) {
        unsigned short* dA = lA + (size_t)buf * BM * 64;
        #pragma unroll
        for (int r = 0; r < BM / 32; ++r) {
            int c = r * 256 + tid, row = c >> 3, gs = c & 7;
            gload16(A + (size_t)row * lda + kt0 + ((gs ^ (row & 7)) * 8),
                    dA + (size_t)(r * 256 + wv * 64) * 8);
        }
        unsigned short* dB = lB + (size_t)buf * BN * 64;
        #pragma unroll
        for (int r = 0; r < BN / 32; ++r) {
            int c = r * 256 + tid, row = c >> 3, gs = c & 7;
            gload16(Bt + (size_t)row * ldb + kt0 + ((gs ^ (row & 7)) * 8),
                    dB + (size_t)(r * 256 + wv * 64) * 8);
        }
    };

    stage(0, 0);
    __syncthreads();                       // K-tile 0 landed
    const int nk = K / 64;
    for (int t = 0; t < nk; ++t) {
        const int buf = t & 1;
        if (t + 1 < nk) stage(buf ^ 1, (t + 1) * 64);   // prefetch next tile
        const unsigned short* cA = lA + (size_t)buf * BM * 64;
        const unsigned short* cB = lB + (size_t)buf * BN * 64;
        #pragma unroll
        for (int kt = 0; kt < 2; ++kt) {
            short8 af[MF], bfr[NF];
            #pragma unroll
            for (int mf = 0; mf < MF; ++mf)
                af[mf] = *(const short8*)&cA[(wr * (BM / 2) + mf * 16 + l15) * 64 +
                                             (((kt * 4 + l4) ^ l7) * 8)];
            #pragma unroll
            for (int nf = 0; nf < NF; ++nf)
                bfr[nf] = *(const short8*)&cB[(wc * (BN / 2) + nf * 16 + l15) * 64 +
                                              (((kt * 4 + l4) ^ l7) * 8)];
            #pragma unroll
            for (int mf = 0; mf < MF; ++mf)
                #pragma unroll
                for (int nf = 0; nf < NF; ++nf)
                    acc[mf][nf] = __builtin_amdgcn_mfma_f32_16x16x32_bf16(af[mf], bfr[nf], acc[mf][nf], 0, 0, 0);
        }
        __syncthreads();                   // drains prefetch (post-compute) + guards buf reuse
    }
}

// ---------------- QKV epilogue (shared) ----------------
// which: 0=Q (scale 1/8, [b,h,s,dk]), 1=K ([b,h,s,dk]), 2=V (transposed [b,h,dk,s])
DEV void qkv_epilogue(f32x4 (&acc)[4][4], const float* __restrict__ bias,
                      unsigned short* __restrict__ out, int which, int m0, int n0) {
    const int lane = threadIdx.x & 63, wv = threadIdx.x >> 6;
    const int wr = wv >> 1, wc = wv & 1, l15 = lane & 15, l4 = lane >> 4;
    #pragma unroll
    for (int mf = 0; mf < 4; ++mf) {
        #pragma unroll
        for (int nf = 0; nf < 4; ++nf) {
            int n = n0 + wc * 64 + nf * 16 + l15;
            int h = n >> 6, dk = n & 63;
            float bv = bias[n];
            if (which == 2) {
                int mg = m0 + wr * 64 + mf * 16 + l4 * 4;  // 4 consecutive rows, same batch
                int b = mg >> 9, s = mg & 511;
                ushort4v o;
                #pragma unroll
                for (int r = 0; r < 4; ++r) o[r] = f2b(acc[mf][nf][r] + bv);
                *(ushort4v*)&out[((size_t)(b * Hc + h) * DKc + dk) * Sc + s] = o;
            } else {
                float scale = (which == 0) ? 0.125f : 1.0f;
                #pragma unroll
                for (int r = 0; r < 4; ++r) {
                    int mg = m0 + wr * 64 + mf * 16 + l4 * 4 + r;
                    int b = mg >> 9, s = mg & 511;
                    out[((size_t)(b * Hc + h) * Sc + s) * DKc + dk] = f2b((acc[mf][nf][r] + bv) * scale);
                }
            }
        }
    }
}

// NOTE: all GEMM kernels use n0 = blockIdx.x (FAST-varying) so the blocks sharing an
// A-panel are dispatched consecutively -> L2 temporal reuse of the 128KB A-tile.
__global__ __launch_bounds__(256) void k_gemm_qkv(
    const unsigned short* __restrict__ X, const unsigned short* __restrict__ Wt,
    const float* __restrict__ bias, unsigned short* __restrict__ out, int which) {
    __shared__ unsigned short lA[2 * 128 * 64], lB[2 * 128 * 64];
    int n0 = blockIdx.x * 128, m0 = blockIdx.y * 128;
    f32x4 acc[4][4];
    gemm_core<128, 128>(X + (size_t)m0 * Dc, Dc, Wt + (size_t)n0 * Dc, Dc, Dc, lA, lB, acc);
    qkv_epilogue(acc, bias, out, which, m0, n0);
}

// merged QKV: grid.z selects {Q,K,V}; all inputs pre-staged in disjoint regions.
__global__ __launch_bounds__(256) void k_gemm_qkv3(
    const unsigned short* __restrict__ Aq, const unsigned short* __restrict__ Ak,
    const unsigned short* __restrict__ Av,
    const unsigned short* __restrict__ Wqt, const unsigned short* __restrict__ Wkt,
    const unsigned short* __restrict__ Wvt,
    const float* __restrict__ bq, const float* __restrict__ bk, const float* __restrict__ bv,
    unsigned short* __restrict__ oq, unsigned short* __restrict__ ok,
    unsigned short* __restrict__ ov) {
    __shared__ unsigned short lA[2 * 128 * 64], lB[2 * 128 * 64];
    const int which = blockIdx.z;
    const unsigned short* X  = which == 0 ? Aq  : (which == 1 ? Ak  : Av);
    const unsigned short* Wt = which == 0 ? Wqt : (which == 1 ? Wkt : Wvt);
    const float* bias        = which == 0 ? bq  : (which == 1 ? bk  : bv);
    unsigned short* out      = which == 0 ? oq  : (which == 1 ? ok  : ov);
    int n0 = blockIdx.x * 128, m0 = blockIdx.y * 128;
    f32x4 acc[4][4];
    gemm_core<128, 128>(X + (size_t)m0 * Dc, Dc, Wt + (size_t)n0 * Dc, Dc, Dc, lA, lB, acc);
    qkv_epilogue(acc, bias, out, which, m0, n0);
}

// ---------------- flash attention: QBLK=256, 8 waves, 2-phase KV-chunk pipeline (verified r21) ----------------
__global__ __launch_bounds__(512) void k_flash(
    const unsigned short* __restrict__ Qb, const unsigned short* __restrict__ Kb,
    const unsigned short* __restrict__ Vt, unsigned short* __restrict__ conc,
    const float* __restrict__ fr, const int* __restrict__ maskp, int b_base) {
    __shared__ unsigned short smem[32768];     // 64KB: lKb[2]@0/4096, lVb[2]@8192/12288, lP@16384
    const int head = blockIdx.y, bl = head >> 3, h = head & 7;
    const int bg = b_base + bl;                // global batch
    const int m0 = (Sc / 256 - 1 - blockIdx.x) * 256;   // LPT: longest blocks first
    const int mv = *maskp;
    const int tid = threadIdx.x, lane = tid & 63, w = tid >> 6;   // w in 0..7
    const int l15 = lane & 15, l4 = lane >> 4;
    const int l7 = l15 & 7;
    const int rw = w * 32;   // wave's q-row base within the 256-row tile
    unsigned short* lP = smem + 16384;         // [256][64]
    constexpr float LOG2E = 1.44269504088896340736f;

    // stage Q tile [256][64] across smem[0..16383] (lKb+lVb regions), source-swizzled
    unsigned short* lQ = smem;
    const unsigned short* Qg = Qb + ((size_t)head * Sc + m0) * DKc;
    #pragma unroll
    for (int r = 0; r < 4; ++r) {
        int c = r * 512 + tid, row = c >> 3, gs = c & 7;
        gload16(Qg + (size_t)row * DKc + ((gs ^ (row & 7)) * 8), lQ + (size_t)(r * 512 + w * 64) * 8);
    }
    __syncthreads();
    short8 qf[2][2];   // [kt][mf]
    #pragma unroll
    for (int kt = 0; kt < 2; ++kt)
        #pragma unroll
        for (int mf = 0; mf < 2; ++mf)
            qf[kt][mf] = *(const short8*)&lQ[(rw + mf * 16 + l15) * 64 + (((kt * 4 + l4) ^ l7) * 8)];
    float frr[8];      // forget_rate * log2e -> scores in log2 domain
    #pragma unroll
    for (int mf = 0; mf < 2; ++mf)
        #pragma unroll
        for (int r = 0; r < 4; ++r)
            frr[mf * 4 + r] = fr[(size_t)bg * Sc + m0 + rw + mf * 16 + l4 * 4 + r] * LOG2E;
    __syncthreads();   // all Q reads done before chunk staging overwrites the region

    f32x4 accO[2][4];  // [mf][dk-group of 16]
    #pragma unroll
    for (int mf = 0; mf < 2; ++mf)
        #pragma unroll
        for (int nf = 0; nf < 4; ++nf)
            accO[mf][nf] = f32x4{0.f, 0.f, 0.f, 0.f};
    float l_run[8];    // per-lane partial row sums (reduced once in epilogue)
    #pragma unroll
    for (int i = 0; i < 8; ++i) l_run[i] = 0.f;

    const unsigned short* Kg0 = Kb + (size_t)head * Sc * DKc;
    const unsigned short* Vg0 = Vt + (size_t)head * DKc * Sc;
    int nc = ((m0 + 254 + mv) >> 6) + 1;   // 64-col chunks needed (allowed: j < i + mv)
    if (nc > 8) nc = 8;
    if (nc < 1) nc = 1;

    // stage chunk 0 into buf 0 (64 rows x 64 cols K, 64 x 64 V^T; 1 gload16/thread each)
    {
        int row = tid >> 3, gs = tid & 7;
        gload16(Kg0 + (size_t)row * DKc + ((gs ^ (row & 7)) * 8), smem + (size_t)(w * 64) * 8);
        gload16(Vg0 + (size_t)row * Sc + ((gs ^ (row & 7)) * 8), smem + 8192 + (size_t)(w * 64) * 8);
    }
    __syncthreads();   // chunk 0 landed

    for (int ci = 0; ci < nc; ++ci) {
        const int buf = ci & 1;
        unsigned short* lK = smem + (size_t)buf * 4096;
        unsigned short* lV = smem + 8192 + (size_t)buf * 4096;
        // prefetch chunk ci+1 into buf^1 (drained by the barrier AFTER compute)
        if (ci + 1 < nc) {
            int n1 = (ci + 1) * 64;
            int row = tid >> 3, gs = tid & 7;
            gload16(Kg0 + (size_t)n1 * DKc + (size_t)row * DKc + ((gs ^ (row & 7)) * 8),
                    smem + (size_t)(buf ^ 1) * 4096 + (size_t)(w * 64) * 8);
            gload16(Vg0 + n1 + (size_t)row * Sc + ((gs ^ (row & 7)) * 8),
                    smem + 8192 + (size_t)(buf ^ 1) * 4096 + (size_t)(w * 64) * 8);
        }
        // ---- compute chunk ci from lK/lV ----
        const int n0c = ci * 64;
        short8 bk[4][2];   // 4 kv-groups x 2 k-halves
        #pragma unroll
        for (int j = 0; j < 4; ++j)
            #pragma unroll
            for (int kt = 0; kt < 2; ++kt)
                bk[j][kt] = *(const short8*)&lK[(j * 16 + l15) * 64 + (((kt * 4 + l4) ^ l7) * 8)];
        #pragma unroll
        for (int mf = 0; mf < 2; ++mf) {
            f32x4 sa[4];
            #pragma unroll
            for (int j = 0; j < 4; ++j) sa[j] = f32x4{0.f, 0.f, 0.f, 0.f};
            #pragma unroll
            for (int kt = 0; kt < 2; ++kt)
                #pragma unroll
                for (int j = 0; j < 4; ++j)
                    sa[j] = __builtin_amdgcn_mfma_f32_16x16x32_bf16(qf[kt][mf], bk[j][kt], sa[j], 0, 0, 0);
            // fixed-max softmax: p = exp2(s) raw, per-lane partial sums only
            #pragma unroll
            for (int r = 0; r < 4; ++r) {
                int rowl = rw + mf * 16 + l4 * 4 + r;
                int rowg = m0 + rowl;
                int prs = rowl & 7;
                float fres = frr[mf * 4 + r];
                float ps = 0.f;
                #pragma unroll
                for (int j = 0; j < 4; ++j) {
                    int colg = n0c + j * 16 + l15;
                    float p = (colg < rowg + mv) ? exp2f(sa[j][r] * fres) : 0.f;
                    ps += p;
                    int gw = j * 2 + (l15 >> 3);    // granule within chunk (0..7)
                    lP[rowl * 64 + ((gw ^ prs) * 8) + l7] = f2b(p);
                }
                l_run[mf * 4 + r] += ps;
            }
        }
        // O += P_chunk * V_chunk (2 k-slots of 32); wave-private lP stripe, in-order
        #pragma unroll
        for (int kl = 0; kl < 2; ++kl) {
            short8 pa[2];
            #pragma unroll
            for (int mf = 0; mf < 2; ++mf)
                pa[mf] = *(const short8*)&lP[(rw + mf * 16 + l15) * 64 + (((kl * 4 + l4) ^ l7) * 8)];
            #pragma unroll
            for (int nf = 0; nf < 4; ++nf) {
                short8 bv8 = *(const short8*)&lV[(nf * 16 + l15) * 64 + (((kl * 4 + l4) ^ l7) * 8)];
                #pragma unroll
                for (int mf = 0; mf < 2; ++mf)
                    accO[mf][nf] = __builtin_amdgcn_mfma_f32_16x16x32_bf16(pa[mf], bv8, accO[mf][nf], 0, 0, 0);
            }
        }
        __syncthreads();   // drains prefetch (post-compute) + guards buf reuse
    }
    // epilogue: reduce row sums across the 16-lane group, normalize; masked rows -> 0
    #pragma unroll
    for (int mf = 0; mf < 2; ++mf)
        #pragma unroll
        for (int r = 0; r < 4; ++r) {
            int rowg = m0 + rw + mf * 16 + l4 * 4 + r;
            float l = l_run[mf * 4 + r];
            #pragma unroll
            for (int o = 1; o < 16; o <<= 1) l += __shfl_xor(l, o);
            float inv = (rowg + mv > 0) ? 1.0f / l : 0.f;
            #pragma unroll
            for (int nf = 0; nf < 4; ++nf) {
                int dk = nf * 16 + l15;
                conc[((size_t)bg * Sc + rowg) * Dc + h * DKc + dk] = f2b(accO[mf][nf][r] * inv);
            }
        }
}

// ---------------- attn_out = concat * Wo + bo + query (residual) -> bf16 ----------------
__global__ __launch_bounds__(256) void k_wo(
    const unsigned short* __restrict__ Cc, const unsigned short* __restrict__ Wot,
    const float* __restrict__ bo, const float* __restrict__ query,
    unsigned short* __restrict__ y) {
    __shared__ unsigned short lA[2 * 128 * 64], lB[2 * 128 * 64];
    int n0 = blockIdx.x * 128, m0 = blockIdx.y * 128;
    f32x4 acc[4][4];
    gemm_core<128, 128>(Cc + (size_t)m0 * Dc, Dc, Wot + (size_t)n0 * Dc, Dc, Dc, lA, lB, acc);
    const int lane = threadIdx.x & 63, wv = threadIdx.x >> 6;
    const int wr = wv >> 1, wc = wv & 1, l15 = lane & 15, l4 = lane >> 4;
    #pragma unroll
    for (int mf = 0; mf < 4; ++mf)
        #pragma unroll
        for (int nf = 0; nf < 4; ++nf) {
            int n = n0 + wc * 64 + nf * 16 + l15;
            float bv = bo[n];
            #pragma unroll
            for (int r = 0; r < 4; ++r) {
                int m = m0 + wr * 64 + mf * 16 + l4 * 4 + r;
                y[(size_t)m * Dc + n] = f2b(acc[mf][nf][r] + bv + query[(size_t)m * Dc + n]);
            }
        }
}

// ---------------- FF1: relu(x*W1 + b1) -> bf16 ----------------
__global__ __launch_bounds__(256) void k_ff1(
    const unsigned short* __restrict__ X, const unsigned short* __restrict__ W1t,
    const float* __restrict__ b1, unsigned short* __restrict__ hb) {
    __shared__ unsigned short lA[2 * 128 * 64], lB[2 * 128 * 64];
    int n0 = blockIdx.x * 128, m0 = blockIdx.y * 128;
    f32x4 acc[4][4];
    gemm_core<128, 128>(X + (size_t)m0 * Dc, Dc, W1t + (size_t)n0 * Dc, Dc, Dc, lA, lB, acc);
    const int lane = threadIdx.x & 63, wv = threadIdx.x >> 6;
    const int wr = wv >> 1, wc = wv & 1, l15 = lane & 15, l4 = lane >> 4;
    #pragma unroll
    for (int mf = 0; mf < 4; ++mf)
        #pragma unroll
        for (int nf = 0; nf < 4; ++nf) {
            int n = n0 + wc * 64 + nf * 16 + l15;
            float bv = b1[n];
            #pragma unroll
            for (int r = 0; r < 4; ++r) {
                int m = m0 + wr * 64 + mf * 16 + l4 * 4 + r;
                hb[(size_t)m * DFc + n] = f2b(fmaxf(acc[mf][nf][r] + bv, 0.f));
            }
        }
}

// ---------------- FF2: h*W2 + b2 + bf16 resid -> bf16 out (DISJOINT buffers) ----------------
__global__ __launch_bounds__(256) void k_ff2bb(
    const unsigned short* __restrict__ Hb, const unsigned short* __restrict__ W2t,
    const float* __restrict__ b2, const unsigned short* __restrict__ residb,
    unsigned short* __restrict__ y) {
    __shared__ unsigned short lA[2 * 128 * 64], lB[2 * 128 * 64];
    int n0 = blockIdx.x * 128, m0 = blockIdx.y * 128;
    f32x4 acc[4][4];
    gemm_core<128, 128>(Hb + (size_t)m0 * DFc, DFc, W2t + (size_t)n0 * DFc, DFc, DFc, lA, lB, acc);
    const int lane = threadIdx.x & 63, wv = threadIdx.x >> 6;
    const int wr = wv >> 1, wc = wv & 1, l15 = lane & 15, l4 = lane >> 4;
    #pragma unroll
    for (int mf = 0; mf < 4; ++mf)
        #pragma unroll
        for (int nf = 0; nf < 4; ++nf) {
            int n = n0 + wc * 64 + nf * 16 + l15;
            float bv = b2[n];
            #pragma unroll
            for (int r = 0; r < 4; ++r) {
                int m = m0 + wr * 64 + mf * 16 + l4 * 4 + r;
                y[(size_t)m * Dc + n] = f2b(acc[mf][nf][r] + bv + b2f(residb[(size_t)m * Dc + n]));
            }
        }
}

// ---------------- LayerNorm, bf16 input (wave per row, D=512); outf/outb optional ----------------
__global__ __launch_bounds__(256) void k_lnb(
    const unsigned short* __restrict__ in, const float* __restrict__ g, const float* __restrict__ be,
    float* __restrict__ outf, unsigned short* __restrict__ outb) {
    int rid = blockIdx.x * 4 + (threadIdx.x >> 6);
    int lane = threadIdx.x & 63;
    ushort8 v = *(const ushort8*)(in + (size_t)rid * Dc + lane * 8);
    float x[8];
    #pragma unroll
    for (int j = 0; j < 8; ++j) x[j] = b2f(v[j]);
    float s = 0.f, ss = 0.f;
    #pragma unroll
    for (int j = 0; j < 8; ++j) { s += x[j]; ss += x[j] * x[j]; }
    #pragma unroll
    for (int o = 1; o < 64; o <<= 1) { s += __shfl_xor(s, o); ss += __shfl_xor(ss, o); }
    float mu = s * (1.f / 512.f);
    float var = ss * (1.f / 512.f) - mu * mu;
    float rs = rsqrtf(var + 1e-5f);
    float4 g0 = ((const float4*)g)[lane * 2], g1v = ((const float4*)g)[lane * 2 + 1];
    float4 e0 = ((const float4*)be)[lane * 2], e1 = ((const float4*)be)[lane * 2 + 1];
    float gg[8] = {g0.x, g0.y, g0.z, g0.w, g1v.x, g1v.y, g1v.z, g1v.w};
    float ee[8] = {e0.x, e0.y, e0.z, e0.w, e1.x, e1.y, e1.z, e1.w};
    float o8[8];
    #pragma unroll
    for (int j = 0; j < 8; ++j) o8[j] = (x[j] - mu) * rs * gg[j] + ee[j];
    if (outf) {
        float4* po = (float4*)(outf + (size_t)rid * Dc);
        float4 w0 = {o8[0], o8[1], o8[2], o8[3]}, w1 = {o8[4], o8[5], o8[6], o8[7]};
        po[lane * 2] = w0; po[lane * 2 + 1] = w1;
    }
    if (outb) {
        ushort8 ob;
        #pragma unroll
        for (int j = 0; j < 8; ++j) ob[j] = f2b(o8[j]);
        *(ushort8*)(outb + (size_t)rid * Dc + lane * 8) = ob;
    }
}

// ---------------- host ----------------
// Memory plan identical to r23 (verified); GEMM grids now (n, m) with n fast-varying.
extern "C" void kernel_launch(void* const* d_in, const int* in_sizes, int n_in,
                              void* d_out, int out_size, void* d_ws, size_t ws_size,
                              hipStream_t stream) {
    const float* query = (const float*)d_in[0];
    const float* key_  = (const float*)d_in[1];
    const float* vals  = (const float*)d_in[2];
    const float* fr    = (const float*)d_in[3];
    const float* Wq = (const float*)d_in[4];  const float* bq = (const float*)d_in[5];
    const float* Wk = (const float*)d_in[6];  const float* bk = (const float*)d_in[7];
    const float* Wv = (const float*)d_in[8];  const float* bv = (const float*)d_in[9];
    const float* Wo = (const float*)d_in[10]; const float* bo = (const float*)d_in[11];
    const float* g1 = (const float*)d_in[12]; const float* be1 = (const float*)d_in[13];
    const float* W1 = (const float*)d_in[14]; const float* b1 = (const float*)d_in[15];
    const float* W2 = (const float*)d_in[16]; const float* b2 = (const float*)d_in[17];
    const float* g2 = (const float*)d_in[18]; const float* be2 = (const float*)d_in[19];
    const int* maskp = (const int*)d_in[20];
    float* out = (float*)d_out;

    // ---- d_out arena ----
    char* ab = (char*)d_out;
    unsigned short* xb    = (unsigned short*)ab;                   // 32 MiB
    unsigned short* conc  = (unsigned short*)ab;
    unsigned short* x1b   = conc;
    unsigned short* keyst = (unsigned short*)(ab + (size_t)32 * 1048576);  // big path
    // chunked-path per-chunk buffers (8 MiB each)
    unsigned short* Qc   = (unsigned short*)(ab + (size_t)32 * 1048576);
    unsigned short* Kc   = (unsigned short*)(ab + (size_t)40 * 1048576);
    unsigned short* Vc   = (unsigned short*)(ab + (size_t)48 * 1048576);
    unsigned short* xst  = (unsigned short*)(ab + (size_t)56 * 1048576);
    unsigned short* xfbc = (unsigned short*)(ab + (size_t)32 * 1048576);   // chunked phase C (16M)

    // ---- ws layout ----
    char* ws = (char*)d_ws;
    unsigned short* Wqt = (unsigned short*)ws;
    unsigned short* Wkt = Wqt + 512 * 512;
    unsigned short* Wvt = Wkt + 512 * 512;
    unsigned short* Wot = Wvt + 512 * 512;
    unsigned short* W1t = Wot + 512 * 512;          // 2048x512
    unsigned short* W2t = W1t + 2048 * 512;         // 512x2048
    char* wend = (char*)(W2t + 512 * 2048);         // = ws + 6,291,456
    size_t wrem = (ws_size > (size_t)(wend - ws)) ? ws_size - (size_t)(wend - ws) : 0;
    const size_t qkvb = (size_t)Mtot * Dc * 2;      // 32 MiB

    const bool bigpath = (wrem >= 3 * qkvb);
    const bool merged  = (wrem >= 4 * qkvb);

    const float* acts[3] = {query, key_, vals};
    const unsigned short* wt3[3] = {Wqt, Wkt, Wvt};
    const float* bs3[3] = {bq, bk, bv};

    if (bigpath) {
        unsigned short* QbF   = (unsigned short*)wend;
        unsigned short* KbF   = QbF + qkvb / 2;
        unsigned short* VtF   = KbF + qkvb / 2;
        unsigned short* valst = VtF + qkvb / 2;     // merged path only (guarded)
        unsigned short* hb     = QbF;               // 64 MiB (QbF+KbF), phase D only
        unsigned short* resid0 = VtF;               // 16 MiB (VtF[0:16M)), phase D only
        unsigned short* ybb    = VtF + (size_t)8 * 1048576;  // 16 MiB (VtF[16M:32M))
        unsigned short* xfb    = KbF;               // 16 MiB used of KbF, phase C only
        const int Mc = 16384;

        if (merged) {
            k_cvt_all<<<dim3(26112), dim3(256), 0, stream>>>(
                Wq, Wk, Wv, Wo, W1, W2, Wqt, Wkt, Wvt, Wot, W1t, W2t,
                query, key_, vals, xb, keyst, valst);
            k_gemm_qkv3<<<dim3(4, Mtot / 128, 3), dim3(256), 0, stream>>>(
                xb, keyst, valst, Wqt, Wkt, Wvt, bq, bk, bv, QbF, KbF, VtF);
        } else {
            k_cvt_all<<<dim3(26112), dim3(256), 0, stream>>>(
                Wq, Wk, Wv, Wo, W1, W2, Wqt, Wkt, Wvt, Wot, W1t, W2t,
                query, key_, vals, xb, keyst, KbF);
            k_gemm_qkv<<<dim3(4, Mtot / 128), dim3(256), 0, stream>>>(KbF,   Wvt, bv, VtF, 2);
            k_gemm_qkv<<<dim3(4, Mtot / 128), dim3(256), 0, stream>>>(keyst, Wkt, bk, KbF, 1);
            k_gemm_qkv<<<dim3(4, Mtot / 128), dim3(256), 0, stream>>>(xb,    Wqt, bq, QbF, 0);
        }

        k_flash<<<dim3(Sc / 256, Bc * Hc), dim3(512), 0, stream>>>(QbF, KbF, VtF, conc, fr, maskp, 0);

        // Phase C: k_wo -> bf16 xfb (KbF, dead); k_lnb -> x1b (over conc)
        k_wo<<<dim3(4, Mtot / 128), dim3(256), 0, stream>>>(conc, Wot, bo, query, xfb);
        k_lnb<<<dim3(Mtot / 4), dim3(256), 0, stream>>>(xfb, g1, be1, (float*)nullptr, x1b);

        // snapshot x1b rows [0, Mc) -> resid0 (VtF[0:16M); xfb/KbF now dead)
        k_copy8<<<dim3(Mc / 4), dim3(256), 0, stream>>>(x1b, resid0, Mc * Dc / 8);

        // Phase D: 2 chunks, descending; ff2 -> bf16 ybb (disjoint), LN2 bf16 -> f32 out
        for (int mb = Mtot - Mc; mb >= 0; mb -= Mc) {
            k_ff1<<<dim3(16, Mc / 128), dim3(256), 0, stream>>>(x1b + (size_t)mb * Dc, W1t, b1, hb);
            k_ff2bb<<<dim3(4, Mc / 128), dim3(256), 0, stream>>>(hb, W2t, b2,
                                                                 mb ? x1b + (size_t)mb * Dc : resid0,
                                                                 ybb);
            k_lnb<<<dim3(Mc / 4), dim3(256), 0, stream>>>(ybb, g2, be2,
                                                          out + (size_t)mb * Dc,
                                                          (unsigned short*)nullptr);
        }
    } else {
        // ---- chunked fallback ----
        int Mc = 128;
        for (int c = 8192; c >= 128; c >>= 1)
            if ((size_t)c * 6144 <= wrem) { Mc = c; break; }
        unsigned short* hb     = (unsigned short*)wend;                        // Mc*4096 B
        unsigned short* resid0 = (unsigned short*)(wend + (size_t)Mc * 4096);  // Mc*1024 B
        unsigned short* ybb    = (unsigned short*)(wend + (size_t)Mc * 5120);  // Mc*1024 B

        k_cvt_w_all<<<dim3(1536), dim3(256), 0, stream>>>(Wq, Wk, Wv, Wo, W1, W2,
                                                          Wqt, Wkt, Wvt, Wot, W1t, W2t);
        unsigned short* out3[3] = {Qc, Kc, Vc};
        for (int cb = 0; cb < Bc / CB; ++cb) {
            for (int p = 0; p < 3; ++p) {
                k_cvt<<<dim3(RC * Dc / 8 / 256), dim3(256), 0, stream>>>(
                    acts[p] + (size_t)cb * RC * Dc, xst, RC * Dc / 8);
                k_gemm_qkv<<<dim3(4, RC / 128), dim3(256), 0, stream>>>(xst, wt3[p], bs3[p], out3[p], p);
            }
            k_flash<<<dim3(Sc / 256, CB * Hc), dim3(512), 0, stream>>>(Qc, Kc, Vc, conc, fr, maskp, cb * CB);
        }
        for (int hp = 0; hp < 2; ++hp) {
            int mb = hp * 16384;
            k_wo<<<dim3(4, 16384 / 128), dim3(256), 0, stream>>>(conc + (size_t)mb * Dc, Wot, bo,
                                                                 query + (size_t)mb * Dc, xfbc);
            k_lnb<<<dim3(16384 / 4), dim3(256), 0, stream>>>(xfbc, g1, be1, (float*)nullptr,
                                                             x1b + (size_t)mb * Dc);
        }
        k_copy8<<<dim3(Mc / 4), dim3(256), 0, stream>>>(x1b, resid0, Mc * Dc / 8);
        for (int mb = Mtot - Mc; mb >= 0; mb -= Mc) {
            k_ff1<<<dim3(16, Mc / 128), dim3(256), 0, stream>>>(x1b + (size_t)mb * Dc, W1t, b1, hb);
            k_ff2bb<<<dim3(4, Mc / 128), dim3(256), 0, stream>>>(hb, W2t, b2,
                                                                 mb ? x1b + (size_t)mb * Dc : resid0,
                                                                 ybb);
            k_lnb<<<dim3(Mc / 4), dim3(256), 0, stream>>>(ybb, g2, be2,
                                                          out + (size_t)mb * Dc,
                                                          (unsigned short*)nullptr);
        }
    }
}